// Round 17
// baseline (667.582 us; speedup 1.0000x reference)
//
#include <hip/hip_runtime.h>
#include <hip/hip_bf16.h>

#define DIV_UP(a,b) (((a)+(b)-1)/(b))

typedef __attribute__((ext_vector_type(8))) short bf16x8;
typedef __attribute__((ext_vector_type(4))) float f32x4;

__device__ __forceinline__ float silu_f(float x) {
    return x / (1.0f + __expf(-x));
}
__device__ __forceinline__ unsigned short f2bf(float x) {
    __hip_bfloat16 h = __float2bfloat16(x);
    return *reinterpret_cast<unsigned short*>(&h);
}
__device__ __forceinline__ float bf2f(unsigned short u) {
    unsigned int v = (unsigned int)u << 16;
    return __uint_as_float(v);
}
__device__ __forceinline__ void split_bf(float x, unsigned short& hi, unsigned short& lo) {
    hi = f2bf(x);
    lo = f2bf(x - bf2f(hi));
}
__device__ __forceinline__ bf16x8 pack8(unsigned int w0, unsigned int w1,
                                        unsigned int w2, unsigned int w3) {
    union { unsigned int u[4]; bf16x8 v; } t;
    t.u[0] = w0; t.u[1] = w1; t.u[2] = w2; t.u[3] = w3;
    return t.v;
}

#define WSLOT 16384   // 128*128 bf16 elements per weight slot (K=128 only)

// ---------------------------------------------------------------------------
// Weight prep (K=128 MLPs): f32 [128][128] -> bf16 hi/lo, transposed.
// ---------------------------------------------------------------------------
__global__ __launch_bounds__(256) void prep_weights_kernel(
    const float* __restrict__ msgW1, const float* __restrict__ msgW2,
    const float* __restrict__ denseW1, const float* __restrict__ denseW2,
    unsigned short* __restrict__ WB)
{
    int slot = blockIdx.y;
    int kind = slot / 3, conv = slot % 3;
    const float* base;
    switch (kind) {
        case 0: base = msgW1; break;
        case 1: base = msgW2; break;
        case 2: base = denseW1; break;
        default: base = denseW2; break;
    }
    const float* W = base + (size_t)conv * 128 * 128;
    int idx = blockIdx.x * 256 + threadIdx.x;
    if (idx >= 16384) return;
    int c = idx >> 7, k = idx & 127;
    float val = W[(size_t)k * 128 + c];
    unsigned short hi, lo;
    split_bf(val, hi, lo);
    WB[(size_t)(2 * slot) * WSLOT + idx]     = hi;
    WB[(size_t)(2 * slot + 1) * WSLOT + idx] = lo;
}

// ---------------------------------------------------------------------------
// CSR build: histogram -> single-block scan with PER-NODE PADDING to x32.
// ---------------------------------------------------------------------------
__global__ __launch_bounds__(256) void hist_kernel(
    const int* __restrict__ nbr, int* __restrict__ counts, int E)
{
    int e = blockIdx.x * 256 + threadIdx.x;
    if (e < E) atomicAdd(&counts[nbr[2 * e]], 1);
}

__global__ __launch_bounds__(1024) void scan_kernel(
    const int* __restrict__ counts, int* __restrict__ peptr, int N)
{
    __shared__ int part[1024];
    const int t = threadIdx.x;
    const int chunk = DIV_UP(N, 1024);
    int s = 0;
    for (int c = 0; c < chunk; ++c) {
        int idx = t * chunk + c;
        if (idx < N) s += (counts[idx] + 31) & ~31;
    }
    part[t] = s;
    __syncthreads();
    for (int off = 1; off < 1024; off <<= 1) {
        int v = (t >= off) ? part[t - off] : 0;
        __syncthreads();
        part[t] += v;
        __syncthreads();
    }
    int pre = (t > 0) ? part[t - 1] : 0;
    for (int c = 0; c < chunk; ++c) {
        int idx = t * chunk + c;
        if (idx < N) { peptr[idx] = pre; pre += (counts[idx] + 31) & ~31; }
    }
    if (t == 1023) peptr[N] = part[1023];
}

// ---------------------------------------------------------------------------
// Fused edge geometry + padded-CSR scatter, SINGLE-LINE chunk layout:
// chunk = 8 subgroups x [k=16][t=4] u16; edge kk writes its 16 rbf values at
// (kk>>2)*128B + k*8B + (kk&3)*2B -- ALL within ONE 128B line (and the 4
// edges of a subgroup jointly fill that line, avoiding write-allocate RMW).
// envs (bf16) and js at padded positions; pad slots pre-zeroed by memset.
// ---------------------------------------------------------------------------
__global__ __launch_bounds__(256) void geom_scatter_kernel(
    const int* __restrict__ nbr, const float* __restrict__ xyz,
    const int* __restrict__ peptr, int* __restrict__ cursor,
    unsigned short* __restrict__ rbfT, unsigned short* __restrict__ envs,
    int* __restrict__ js, int E)
{
    int e = blockIdx.x * 256 + threadIdx.x;
    if (e >= E) return;
    int i = nbr[2 * e], j = nbr[2 * e + 1];
    float dx = xyz[3 * j + 0] - xyz[3 * i + 0];
    float dy = xyz[3 * j + 1] - xyz[3 * i + 1];
    float dz = xyz[3 * j + 2] - xyz[3 * i + 2];
    float dist = sqrtf(dx * dx + dy * dy + dz * dz);
    float x = dist * 0.3141592653589793f;   // pi/CUTOFF
    float s, c;
    __sincosf(x, &s, &c);
    float env = (dist < 10.0f) ? 0.5f * (c + 1.0f) : 0.0f;
    float inv_env = env / dist;
    float two_c = 2.0f * c;
    float sm1 = 0.0f, s0 = s;
    unsigned short ob[16];
    #pragma unroll
    for (int k = 0; k < 16; ++k) {
        ob[k] = f2bf(s0 * inv_env);
        float s1 = two_c * s0 - sm1;
        sm1 = s0; s0 = s1;
    }
    int p = peptr[i] + atomicAdd(&cursor[i], 1);
    unsigned short* tb = rbfT + (size_t)(p >> 5) * 512;
    const int kk = p & 31;
    const int base = ((kk >> 2) << 6) | (kk & 3);   // u16 index: subgroup*64 + t
    #pragma unroll
    for (int r = 0; r < 16; ++r)
        tb[base + r * 4] = ob[r];
    envs[p] = f2bf(env);
    js[p] = j;
}

// ---------------------------------------------------------------------------
// S0 = concat(S[N,124], res_embed[cg_z][N,4])  -> [N,128]
// ---------------------------------------------------------------------------
__global__ __launch_bounds__(256) void concat_s_kernel(
    const float* __restrict__ S, const float* __restrict__ res_embed,
    const int* __restrict__ z, float* __restrict__ S0, int N)
{
    int idx = blockIdx.x * 256 + threadIdx.x;
    if (idx >= N * 128) return;
    int n = idx >> 7, c = idx & 127;
    float val = (c < 124) ? S[n * 124 + c] : res_embed[z[n] * 4 + (c - 124)];
    S0[idx] = val;
}

// ---------------------------------------------------------------------------
// Split-bf16 MFMA two-stage MLP, K=128, LDS 56 KB (r6-proven).
// ---------------------------------------------------------------------------
template<int MT, bool PREACT, bool RESID, typename OutT>
__global__ __launch_bounds__(256) void mlp2_mfma_kernel(
    const float* __restrict__ X,
    const unsigned short* __restrict__ W1hi, const unsigned short* __restrict__ W1lo,
    const float* __restrict__ b1,
    const unsigned short* __restrict__ W2hi, const unsigned short* __restrict__ W2lo,
    const float* __restrict__ b2,
    OutT* __restrict__ Y, int nrows)
{
    constexpr int RB   = MT / 16;
    constexpr int ROWB = 256;
    __shared__ __align__(16) unsigned short XHhi[MT * 128];
    __shared__ __align__(16) unsigned short XHlo[MT * 128];
    __shared__ __align__(16) unsigned short WS[128 * 128];

    const int tid  = threadIdx.x;
    const int wave = tid >> 6;
    const int lane = tid & 63;
    const int l15  = lane & 15;
    const int kg   = lane >> 4;
    const int row0 = blockIdx.x * MT;

    for (int idx = tid; idx < MT * 32; idx += 256) {
        int r = idx >> 5, q = idx & 31;
        int gr = row0 + r;
        float4 xv = make_float4(0.f, 0.f, 0.f, 0.f);
        if (gr < nrows) xv = *(const float4*)(X + (size_t)gr * 128 + 4 * q);
        if (PREACT) { xv.x = silu_f(xv.x); xv.y = silu_f(xv.y);
                      xv.z = silu_f(xv.z); xv.w = silu_f(xv.w); }
        ushort4 h, l;
        split_bf(xv.x, h.x, l.x); split_bf(xv.y, h.y, l.y);
        split_bf(xv.z, h.z, l.z); split_bf(xv.w, h.w, l.w);
        int off = (8 * q) ^ ((r & 7) << 4);
        *(ushort4*)((char*)XHhi + r * ROWB + off) = h;
        *(ushort4*)((char*)XHlo + r * ROWB + off) = l;
    }

    f32x4 acc[RB][2];

    #define STAGE_W(WPTR)                                                       \
        for (int idx = tid; idx < 2048; idx += 256) {                           \
            int r = idx >> 4;                                                   \
            int byt = (idx & 15) * 16;                                          \
            *(uint4*)((char*)WS + r * ROWB + (byt ^ ((r & 7) << 4))) =          \
                *(const uint4*)((WPTR) + (size_t)idx * 8);                      \
        }

    #define PASS(WITH_LO)                                                       \
        _Pragma("unroll")                                                       \
        for (int kk = 0; kk < 4; ++kk) {                                        \
            const int kbyte = kk * 64 + kg * 16;                                \
            bf16x8 ah[RB], al[RB];                                              \
            _Pragma("unroll")                                                   \
            for (int rb = 0; rb < RB; ++rb) {                                   \
                int r = 16 * rb + l15;                                          \
                int off = kbyte ^ ((r & 7) << 4);                               \
                ah[rb] = *(const bf16x8*)((const char*)XHhi + r * ROWB + off);  \
                if (WITH_LO)                                                    \
                    al[rb] = *(const bf16x8*)((const char*)XHlo + r * ROWB + off); \
            }                                                                   \
            _Pragma("unroll")                                                   \
            for (int cbi = 0; cbi < 2; ++cbi) {                                 \
                int rw = 16 * (wave + 4 * cbi) + l15;                           \
                int offw = kbyte ^ ((rw & 7) << 4);                             \
                bf16x8 bw = *(const bf16x8*)((const char*)WS + rw * ROWB + offw); \
                _Pragma("unroll")                                               \
                for (int rb = 0; rb < RB; ++rb) {                               \
                    f32x4 t = acc[rb][cbi];                                     \
                    t = __builtin_amdgcn_mfma_f32_16x16x32_bf16(ah[rb], bw, t, 0, 0, 0); \
                    if (WITH_LO)                                                \
                        t = __builtin_amdgcn_mfma_f32_16x16x32_bf16(al[rb], bw, t, 0, 0, 0); \
                    acc[rb][cbi] = t;                                           \
                }                                                               \
            }                                                                   \
        }

    #pragma unroll
    for (int a = 0; a < RB; ++a) { acc[a][0] = (f32x4){0,0,0,0}; acc[a][1] = (f32x4){0,0,0,0}; }
    STAGE_W(W1hi)
    __syncthreads();
    PASS(true)
    __syncthreads();
    STAGE_W(W1lo)
    __syncthreads();
    PASS(false)
    __syncthreads();

    #pragma unroll
    for (int cbi = 0; cbi < 2; ++cbi) {
        int col = 16 * (wave + 4 * cbi) + l15;
        float b1v = b1[col];
        #pragma unroll
        for (int rb = 0; rb < RB; ++rb)
            #pragma unroll
            for (int i = 0; i < 4; ++i) {
                int r = 16 * rb + kg * 4 + i;
                float h = silu_f(acc[rb][cbi][i] + b1v);
                unsigned short hh, hl;
                split_bf(h, hh, hl);
                int off = (2 * col) ^ ((r & 7) << 4);
                *(unsigned short*)((char*)XHhi + r * ROWB + off) = hh;
                *(unsigned short*)((char*)XHlo + r * ROWB + off) = hl;
            }
    }
    #pragma unroll
    for (int a = 0; a < RB; ++a) { acc[a][0] = (f32x4){0,0,0,0}; acc[a][1] = (f32x4){0,0,0,0}; }
    STAGE_W(W2hi)
    __syncthreads();
    PASS(true)
    __syncthreads();
    STAGE_W(W2lo)
    __syncthreads();
    PASS(false)
    #undef PASS
    #undef STAGE_W

    #pragma unroll
    for (int cbi = 0; cbi < 2; ++cbi) {
        int col = 16 * (wave + 4 * cbi) + l15;
        float b2v = b2[col];
        #pragma unroll
        for (int rb = 0; rb < RB; ++rb)
            #pragma unroll
            for (int i = 0; i < 4; ++i) {
                int gr = row0 + 16 * rb + kg * 4 + i;
                if (gr < nrows) {
                    size_t off = (size_t)gr * 128 + col;
                    float val = acc[rb][cbi][i] + b2v;
                    if (RESID) val += (float)Y[off];
                    if constexpr (sizeof(OutT) == 2)
                        Y[off] = __float2bfloat16(val);
                    else
                        Y[off] = val;
                }
            }
    }
}

// ---------------------------------------------------------------------------
// Generic two-stage fp32 MLP, ROWS/RR template params + k-loop UNROLL 6.
// ---------------------------------------------------------------------------
template<int K, int ROWS, int RR, bool PREACT, bool RESID, typename OutT>
__global__ __launch_bounds__(256) void mlp2_kernel(
    const float* __restrict__ X, int ldX,
    const float* __restrict__ W1, const float* __restrict__ b1,
    const float* __restrict__ W2, const float* __restrict__ b2,
    OutT* __restrict__ Y, int ldY, int nrows)
{
    constexpr int NC = (K + 31) / 32;
    __shared__ float Xs[ROWS * K];
    __shared__ float Hs[ROWS * K];
    const int tid = threadIdx.x;
    const int row0 = blockIdx.x * ROWS;

    for (int idx = tid; idx < ROWS * K; idx += 256) {
        int r = idx / K, c = idx - r * K;
        int gr = row0 + r;
        float x = (gr < nrows) ? X[(size_t)gr * ldX + c] : 0.0f;
        if (PREACT) x = silu_f(x);
        Xs[idx] = x;
    }
    __syncthreads();

    const int cc = tid & 31;
    const int r0 = (tid >> 5) * RR;

    float acc[NC][RR];
    #pragma unroll
    for (int jc = 0; jc < NC; ++jc) {
        int col = cc + 32 * jc;
        float bv = (col < K) ? b1[col] : 0.0f;
        #pragma unroll
        for (int rr = 0; rr < RR; ++rr) acc[jc][rr] = bv;
    }
    #pragma unroll 6
    for (int k = 0; k < K; ++k) {
        float w[NC];
        #pragma unroll
        for (int jc = 0; jc < NC; ++jc) {
            int col = cc + 32 * jc;
            w[jc] = (col < K) ? W1[k * K + col] : 0.0f;
        }
        float xv[RR];
        #pragma unroll
        for (int rr = 0; rr < RR; ++rr) xv[rr] = Xs[(r0 + rr) * K + k];
        #pragma unroll
        for (int jc = 0; jc < NC; ++jc)
            #pragma unroll
            for (int rr = 0; rr < RR; ++rr)
                acc[jc][rr] = fmaf(xv[rr], w[jc], acc[jc][rr]);
    }
    #pragma unroll
    for (int jc = 0; jc < NC; ++jc) {
        int col = cc + 32 * jc;
        if (col < K) {
            #pragma unroll
            for (int rr = 0; rr < RR; ++rr)
                Hs[(r0 + rr) * K + col] = silu_f(acc[jc][rr]);
        }
    }
    __syncthreads();

    #pragma unroll
    for (int jc = 0; jc < NC; ++jc) {
        int col = cc + 32 * jc;
        float bv = (col < K) ? b2[col] : 0.0f;
        #pragma unroll
        for (int rr = 0; rr < RR; ++rr) acc[jc][rr] = bv;
    }
    #pragma unroll 6
    for (int k = 0; k < K; ++k) {
        float w[NC];
        #pragma unroll
        for (int jc = 0; jc < NC; ++jc) {
            int col = cc + 32 * jc;
            w[jc] = (col < K) ? W2[k * K + col] : 0.0f;
        }
        float xv[RR];
        #pragma unroll
        for (int rr = 0; rr < RR; ++rr) xv[rr] = Hs[(r0 + rr) * K + k];
        #pragma unroll
        for (int jc = 0; jc < NC; ++jc)
            #pragma unroll
            for (int rr = 0; rr < RR; ++rr)
                acc[jc][rr] = fmaf(xv[rr], w[jc], acc[jc][rr]);
    }
    #pragma unroll
    for (int jc = 0; jc < NC; ++jc) {
        int col = cc + 32 * jc;
        if (col < K) {
            #pragma unroll
            for (int rr = 0; rr < RR; ++rr) {
                int gr = row0 + r0 + rr;
                if (gr < nrows) {
                    size_t off = (size_t)gr * ldY + col;
                    float val = acc[jc][rr];
                    if (RESID) val += (float)Y[off];
                    if constexpr (sizeof(OutT) == 2)
                        Y[off] = __float2bfloat16(val);
                    else
                        Y[off] = val;
                }
            }
        }
    }
}

// ---------------------------------------------------------------------------
// Register-direct MFMA gather, COLUMN-SPLIT + subgroup-packed A (2x ushort4).
// ---------------------------------------------------------------------------
__global__ __launch_bounds__(256) void gather_mfma_kernel(
    const int* __restrict__ peptr,
    const unsigned short* __restrict__ rbfT,   // [EPAD/32][512] subgroup-packed
    const unsigned short* __restrict__ envs,   // [EPAD] bf16 (pads zero)
    const int* __restrict__ js,                // [EPAD]      (pads zero)
    const unsigned short* __restrict__ phi,    // [N][128] bf16
    const float* __restrict__ distW, const float* __restrict__ distb,
    float* __restrict__ v, int N)
{
    const int wv = blockIdx.x * 4 + (threadIdx.x >> 6);
    const int lane = threadIdx.x & 63;
    const int n = wv >> 1;
    const int h = wv & 1;               // column half: cols 64h .. 64h+63
    if (n >= N) return;
    const int l15 = lane & 15;
    const int lg  = lane >> 4;

    f32x4 acc[4];
    float eac[4];
    #pragma unroll
    for (int cb = 0; cb < 4; ++cb) { acc[cb] = (f32x4){0,0,0,0}; eac[cb] = 0.f; }

    const int p0 = peptr[n], p1 = peptr[n + 1];

    for (int p = p0; p < p1; p += 32) {
        // A-frag: af[i] = rbf[l15][edge 8*lg+i]; edges 8lg..8lg+3 in subgroup
        // 2lg (t=i), 8lg+4..8lg+7 in subgroup 2lg+1 (t=i-4).
        const unsigned short* tb = rbfT + (size_t)(p >> 5) * 512;
        ushort4 a0 = *(const ushort4*)(tb + 128 * lg + l15 * 4);
        ushort4 a1 = *(const ushort4*)(tb + 128 * lg + 64 + l15 * 4);
        bf16x8 af = pack8((unsigned int)a0.x | ((unsigned int)a0.y << 16),
                          (unsigned int)a0.z | ((unsigned int)a0.w << 16),
                          (unsigned int)a1.x | ((unsigned int)a1.y << 16),
                          (unsigned int)a1.z | ((unsigned int)a1.w << 16));

        bf16x8 a2f = (bf16x8){0,0,0,0,0,0,0,0};
        if (l15 == 0)
            a2f = *(const bf16x8*)(envs + p + 8 * lg);

        int4 j03 = *(const int4*)(js + p + 8 * lg);
        int4 j47 = *(const int4*)(js + p + 8 * lg + 4);

        const unsigned short* pb0 = phi + (size_t)j03.x * 128 + 64 * h + l15;
        const unsigned short* pb1 = phi + (size_t)j03.y * 128 + 64 * h + l15;
        const unsigned short* pb2 = phi + (size_t)j03.z * 128 + 64 * h + l15;
        const unsigned short* pb3 = phi + (size_t)j03.w * 128 + 64 * h + l15;
        const unsigned short* pb4 = phi + (size_t)j47.x * 128 + 64 * h + l15;
        const unsigned short* pb5 = phi + (size_t)j47.y * 128 + 64 * h + l15;
        const unsigned short* pb6 = phi + (size_t)j47.z * 128 + 64 * h + l15;
        const unsigned short* pb7 = phi + (size_t)j47.w * 128 + 64 * h + l15;

        #pragma unroll
        for (int cbi = 0; cbi < 4; ++cbi) {
            const int o = cbi * 16;
            unsigned int b0 = (unsigned int)pb0[o] | ((unsigned int)pb1[o] << 16);
            unsigned int b1 = (unsigned int)pb2[o] | ((unsigned int)pb3[o] << 16);
            unsigned int b2 = (unsigned int)pb4[o] | ((unsigned int)pb5[o] << 16);
            unsigned int b3 = (unsigned int)pb6[o] | ((unsigned int)pb7[o] << 16);
            bf16x8 bf = pack8(b0, b1, b2, b3);
            acc[cbi] = __builtin_amdgcn_mfma_f32_16x16x32_bf16(af, bf, acc[cbi], 0, 0, 0);
            f32x4 z = (f32x4){0, 0, 0, 0};
            z = __builtin_amdgcn_mfma_f32_16x16x32_bf16(a2f, bf, z, 0, 0, 0);
            eac[cbi] += z[0];
        }
    }

    #pragma unroll
    for (int cbi = 0; cbi < 4; ++cbi) {
        int col = 64 * h + cbi * 16 + l15;
        float part = acc[cbi][0] * distW[(lg * 4 + 0) * 128 + col];
        part = fmaf(acc[cbi][1], distW[(lg * 4 + 1) * 128 + col], part);
        part = fmaf(acc[cbi][2], distW[(lg * 4 + 2) * 128 + col], part);
        part = fmaf(acc[cbi][3], distW[(lg * 4 + 3) * 128 + col], part);
        if (lg == 0) part = fmaf(eac[cbi], distb[col], part);
        part += __shfl_xor(part, 16, 64);
        part += __shfl_xor(part, 32, 64);
        if (lane < 16) v[(size_t)n * 128 + col] = part;
    }
}

// ---------------------------------------------------------------------------
// Fused heads (r12-proven): bbA, bbT, scA, scS per node in one wave.
// ---------------------------------------------------------------------------
__global__ __launch_bounds__(256) void fused_heads_kernel(
    const float* __restrict__ S0,
    const float* __restrict__ bbaW1, const float* __restrict__ bbab1,
    const float* __restrict__ bbaW2, const float* __restrict__ bbab2,
    const float* __restrict__ bbtW1, const float* __restrict__ bbtb1,
    const float* __restrict__ bbtW2, const float* __restrict__ bbtb2,
    const float* __restrict__ scaW1, const float* __restrict__ scab1,
    const float* __restrict__ scaW2, const float* __restrict__ scab2,
    float* __restrict__ bbA, float* __restrict__ bbT,
    float* __restrict__ scA, float* __restrict__ scS, int N)
{
    const int wid = threadIdx.x >> 6;
    const int lane = threadIdx.x & 63;
    const int n = blockIdx.x * 4 + wid;
    if (n >= N) return;

    float x0 = S0[(size_t)n * 128 + lane];
    float x1 = S0[(size_t)n * 128 + 64 + lane];
    float s0 = silu_f(x0), s1 = silu_f(x1);

    // ---- bba (M=3, K=128) ----
    float ba[3];
    #pragma unroll
    for (int m = 0; m < 3; ++m)
        ba[m] = fmaf(s0, bbaW1[lane * 3 + m], s1 * bbaW1[(lane + 64) * 3 + m]);
    #pragma unroll
    for (int m = 0; m < 3; ++m)
        #pragma unroll
        for (int off = 32; off > 0; off >>= 1)
            ba[m] += __shfl_xor(ba[m], off, 64);
    float bbo[3];
    {
        float tm[3];
        #pragma unroll
        for (int m = 0; m < 3; ++m) tm[m] = silu_f(ba[m] + bbab1[m]);
        #pragma unroll
        for (int mm = 0; mm < 3; ++mm) {
            float o = bbab2[mm];
            #pragma unroll
            for (int m = 0; m < 3; ++m) o = fmaf(tm[m], bbaW2[m * 3 + mm], o);
            bbo[mm] = o;
        }
    }
    if (lane < 3) {
        float ov = bbo[0];
        if (lane == 1) ov = bbo[1];
        if (lane == 2) ov = bbo[2];
        bbA[(size_t)n * 3 + lane] = ov;
    }

    // ---- bbt (M=3, K=131 = S0 ++ bbA) ----
    float bt[3];
    #pragma unroll
    for (int m = 0; m < 3; ++m)
        bt[m] = fmaf(s0, bbtW1[lane * 3 + m], s1 * bbtW1[(lane + 64) * 3 + m]);
    #pragma unroll
    for (int m = 0; m < 3; ++m)
        #pragma unroll
        for (int off = 32; off > 0; off >>= 1)
            bt[m] += __shfl_xor(bt[m], off, 64);
    #pragma unroll
    for (int m = 0; m < 3; ++m)
        #pragma unroll
        for (int t = 0; t < 3; ++t)
            bt[m] = fmaf(silu_f(bbo[t]), bbtW1[(128 + t) * 3 + m], bt[m]);
    {
        float tm[3], bto[3];
        #pragma unroll
        for (int m = 0; m < 3; ++m) tm[m] = silu_f(bt[m] + bbtb1[m]);
        #pragma unroll
        for (int mm = 0; mm < 3; ++mm) {
            float o = bbtb2[mm];
            #pragma unroll
            for (int m = 0; m < 3; ++m) o = fmaf(tm[m], bbtW2[m * 3 + mm], o);
            bto[mm] = o;
        }
        if (lane < 3) {
            float ov = bto[0];
            if (lane == 1) ov = bto[1];
            if (lane == 2) ov = bto[2];
            bbT[(size_t)n * 3 + lane] = ov;
        }
    }

    // ---- sca (M=10, K=128) ----
    float sa[10];
    #pragma unroll
    for (int m = 0; m < 10; ++m)
        sa[m] = fmaf(s0, scaW1[lane * 10 + m], s1 * scaW1[(lane + 64) * 10 + m]);
    #pragma unroll
    for (int m = 0; m < 10; ++m)
        #pragma unroll
        for (int off = 32; off > 0; off >>= 1)
            sa[m] += __shfl_xor(sa[m], off, 64);
    float sco[10];
    {
        float tm[10];
        #pragma unroll
        for (int m = 0; m < 10; ++m) tm[m] = silu_f(sa[m] + scab1[m]);
        #pragma unroll
        for (int mm = 0; mm < 10; ++mm) {
            float o = scab2[mm];
            #pragma unroll
            for (int m = 0; m < 10; ++m) o = fmaf(tm[m], scaW2[m * 10 + mm], o);
            sco[mm] = o;
        }
    }
    float scv = sco[0];
    #pragma unroll
    for (int m = 1; m < 10; ++m)
        if (lane == m) scv = sco[m];
    if (lane < 10) scA[(size_t)n * 10 + lane] = scv;

    // ---- scS = concat(S0, scA, pad) ----
    scS[(size_t)n * 140 + lane] = x0;
    scS[(size_t)n * 140 + 64 + lane] = x1;
    if (lane < 12) scS[(size_t)n * 140 + 128 + lane] = (lane < 10) ? scv : 0.0f;
}

// ---------------------------------------------------------------------------
// Small head: out = silu( silu(x) @ W1 + b1 ) @ W2 + b2   (final linear)
// ---------------------------------------------------------------------------
template<int M>
__global__ __launch_bounds__(256) void head_kernel(
    const float* __restrict__ X, int ldX, int K1,
    const float* __restrict__ X2, int ldX2, int K2,
    const float* __restrict__ W1, const float* __restrict__ b1,
    const float* __restrict__ W2, const float* __restrict__ b2,
    float* __restrict__ out, int ldOut, int nrows)
{
    const int wid = threadIdx.x >> 6;
    const int lane = threadIdx.x & 63;
    const int n = blockIdx.x * 4 + wid;
    if (n >= nrows) return;
    const int K = K1 + K2;
    float sx[3];
    #pragma unroll
    for (int t = 0; t < 3; ++t) {
        int k = lane + 64 * t;
        float v = 0.0f;
        if (k < K1) v = X[(size_t)n * ldX + k];
        else if (k < K) v = X2[(size_t)n * ldX2 + (k - K1)];
        sx[t] = (k < K) ? silu_f(v) : 0.0f;
    }
    float acc[M];
    #pragma unroll
    for (int m = 0; m < M; ++m) {
        float a = 0.0f;
        #pragma unroll
        for (int t = 0; t < 3; ++t) {
            int k = lane + 64 * t;
            if (k < K) a = fmaf(sx[t], W1[k * M + m], a);
        }
        acc[m] = a;
    }
    #pragma unroll
    for (int m = 0; m < M; ++m) {
        #pragma unroll
        for (int off = 32; off > 0; off >>= 1)
            acc[m] += __shfl_xor(acc[m], off, 64);
    }
    float tm[M];
    #pragma unroll
    for (int m = 0; m < M; ++m) tm[m] = silu_f(acc[m] + b1[m]);
    if (lane < M) {
        float o = b2[lane];
        #pragma unroll
        for (int m = 0; m < M; ++m) o = fmaf(tm[m], W2[m * M + lane], o);
        out[(size_t)n * ldOut + lane] = o;
    }
}

// ---------------------------------------------------------------------------
// Output assembly: out[N][13][3]
// ---------------------------------------------------------------------------
__global__ __launch_bounds__(256) void assemble_kernel(
    const int* __restrict__ z,
    const float* __restrict__ bbde, const float* __restrict__ scde,
    const float* __restrict__ bbA, const float* __restrict__ bbT,
    const float* __restrict__ scA, const float* __restrict__ scT,
    float* __restrict__ out, int N)
{
    int idx = blockIdx.x * 256 + threadIdx.x;
    if (idx >= N * 39) return;
    int n = idx / 39;
    int s = idx - n * 39;
    int row = s / 3;
    int col = s - row * 3;
    float val;
    if (row < 3) {
        if (col == 0)      val = bbde[z[n] * 3 + row];
        else if (col == 1) val = bbA[n * 3 + row];
        else               val = bbT[n * 3 + row];
    } else {
        int r = row - 3;
        if (col == 0)      val = scde[z[n] * 10 + r];
        else if (col == 1) val = scA[n * 10 + r];
        else               val = scT[n * 10 + r];
    }
    out[idx] = val;
}

extern "C" void kernel_launch(void* const* d_in, const int* in_sizes, int n_in,
                              void* d_out, int out_size, void* d_ws, size_t ws_size,
                              hipStream_t stream)
{
    const int*   cg_z        = (const int*)d_in[0];
    const float* cg_xyz      = (const float*)d_in[1];
    const int*   nbr         = (const int*)d_in[2];
    // d_in[3] = mapping (unused by reference)
    const float* S_in        = (const float*)d_in[4];
    const float* res_embed   = (const float*)d_in[5];
    const float* msg_W1      = (const float*)d_in[6];
    const float* msg_b1      = (const float*)d_in[7];
    const float* msg_W2      = (const float*)d_in[8];
    const float* msg_b2      = (const float*)d_in[9];
    const float* dist_W      = (const float*)d_in[10];
    const float* dist_b      = (const float*)d_in[11];
    const float* dense_W1    = (const float*)d_in[12];
    const float* dense_b1    = (const float*)d_in[13];
    const float* dense_W2    = (const float*)d_in[14];
    const float* dense_b2    = (const float*)d_in[15];
    const float* bb_dist_emb = (const float*)d_in[16];
    const float* sc_dist_emb = (const float*)d_in[17];
    const float* bba_W1      = (const float*)d_in[18];
    const float* bba_b1      = (const float*)d_in[19];
    const float* bba_W2      = (const float*)d_in[20];
    const float* bba_b2      = (const float*)d_in[21];
    const float* sca_W1      = (const float*)d_in[22];
    const float* sca_b1      = (const float*)d_in[23];
    const float* sca_W2      = (const float*)d_in[24];
    const float* sca_b2      = (const float*)d_in[25];
    const float* bbt_W1      = (const float*)d_in[26];
    const float* bbt_b1      = (const float*)d_in[27];
    const float* bbt_W2      = (const float*)d_in[28];
    const float* bbt_b2      = (const float*)d_in[29];
    const float* sct_W1      = (const float*)d_in[30];
    const float* sct_b1      = (const float*)d_in[31];
    const float* sct_W2      = (const float*)d_in[32];
    const float* sct_b2      = (const float*)d_in[33];
    const float* ft_W1       = (const float*)d_in[34];
    const float* ft_b1       = (const float*)d_in[35];
    const float* ft_W2       = (const float*)d_in[36];
    const float* ft_b2       = (const float*)d_in[37];

    const int N = in_sizes[0];
    const int E = in_sizes[2] / 2;
    const int EPAD = ((E + 31 * N) / 32) * 32 + 32;   // padded-edge upper bound

    unsigned short* WB   = (unsigned short*)d_ws;                      // 24*WSLOT
    unsigned short* rbfT = WB + (size_t)24 * WSLOT;                    // EPAD*16 (subgroup-packed)
    unsigned short* envs = rbfT + (size_t)EPAD * 16;                   // EPAD
    int*            js   = (int*)(envs + (size_t)EPAD);                // EPAD
    float* ws   = (float*)(js + (size_t)EPAD);
    float* S0   = ws;  ws += (size_t)N * 128;
    float* V    = ws;  ws += (size_t)N * 128;
    float* scS  = ws;  ws += (size_t)N * 140;
    float* bbA  = ws;  ws += (size_t)N * 3;
    float* bbT  = ws;  ws += (size_t)N * 3;
    float* scA  = ws;  ws += (size_t)N * 10;
    float* scT  = ws;  ws += (size_t)N * 10;
    __hip_bfloat16* PHI = (__hip_bfloat16*)ws;  ws += (size_t)N * 64;  // N*128 bf16
    int* peptr  = (int*)ws;  ws = (float*)((int*)ws + (N + 1));
    int* counts = (int*)ws;  ws = (float*)((int*)ws + N);
    int* cursor = (int*)ws;  ws = (float*)((int*)ws + N);

    // Zero padded edge region (rbfT|envs|js contiguous) + counts/cursor.
    (void)hipMemsetAsync(rbfT, 0, (size_t)EPAD * 38, stream);
    (void)hipMemsetAsync(counts, 0, (size_t)2 * N * sizeof(int), stream);

    prep_weights_kernel<<<dim3(64, 12), 256, 0, stream>>>(
        msg_W1, msg_W2, dense_W1, dense_W2, WB);

    hist_kernel<<<DIV_UP(E, 256), 256, 0, stream>>>(nbr, counts, E);
    scan_kernel<<<1, 1024, 0, stream>>>(counts, peptr, N);
    geom_scatter_kernel<<<DIV_UP(E, 256), 256, 0, stream>>>(
        nbr, cg_xyz, peptr, cursor, rbfT, envs, js, E);

    concat_s_kernel<<<DIV_UP(N * 128, 256), 256, 0, stream>>>(S_in, res_embed, cg_z, S0, N);

    #define WHI(kind, conv) (WB + (size_t)(2 * ((kind) * 3 + (conv))) * WSLOT)
    #define WLO(kind, conv) (WB + (size_t)(2 * ((kind) * 3 + (conv)) + 1) * WSLOT)

    for (int i = 0; i < 3; ++i) {
        mlp2_mfma_kernel<48, false, false, __hip_bfloat16>
            <<<DIV_UP(N, 48), 256, 0, stream>>>(
            S0, WHI(0, i), WLO(0, i), msg_b1 + i * 128,
            WHI(1, i), WLO(1, i), msg_b2 + i * 128, PHI, N);
        gather_mfma_kernel<<<DIV_UP(2 * N, 4), 256, 0, stream>>>(
            peptr, rbfT, envs, js, (const unsigned short*)PHI,
            dist_W + (size_t)i * 16 * 128, dist_b + i * 128, V, N);
        mlp2_mfma_kernel<48, true, true, float>
            <<<DIV_UP(N, 48), 256, 0, stream>>>(
            V, WHI(2, i), WLO(2, i), dense_b1 + i * 128,
            WHI(3, i), WLO(3, i), dense_b2 + i * 128, S0, N);
    }

    fused_heads_kernel<<<DIV_UP(N, 4), 256, 0, stream>>>(
        S0,
        bba_W1, bba_b1, bba_W2, bba_b2,
        bbt_W1, bbt_b1, bbt_W2, bbt_b2,
        sca_W1, sca_b1, sca_W2, sca_b2,
        bbA, bbT, scA, scS, N);

    for (int i = 0; i < 3; ++i) {
        mlp2_kernel<138, 16, 2, true, true, float><<<DIV_UP(N, 16), 256, 0, stream>>>(
            scS, 140, sct_W1 + (size_t)i * 138 * 138, sct_b1 + i * 138,
            sct_W2 + (size_t)i * 138 * 138, sct_b2 + i * 138, scS, 140, N);
    }
    head_kernel<10><<<DIV_UP(N, 4), 256, 0, stream>>>(
        scS, 140, 138, scS, 0, 0, ft_W1, ft_b1, ft_W2, ft_b2, scT, 10, N);

    assemble_kernel<<<DIV_UP(N * 39, 256), 256, 0, stream>>>(
        cg_z, bb_dist_emb, sc_dist_emb, bbA, bbT, scA, scT, (float*)d_out, N);

    #undef WHI
    #undef WLO
}

// Round 18
// 637.082 us; speedup vs baseline: 1.0479x; 1.0479x over previous
//
#include <hip/hip_runtime.h>
#include <hip/hip_bf16.h>

#define DIV_UP(a,b) (((a)+(b)-1)/(b))

typedef __attribute__((ext_vector_type(8))) short bf16x8;
typedef __attribute__((ext_vector_type(4))) float f32x4;

__device__ __forceinline__ float silu_f(float x) {
    return x / (1.0f + __expf(-x));
}
__device__ __forceinline__ unsigned short f2bf(float x) {
    __hip_bfloat16 h = __float2bfloat16(x);
    return *reinterpret_cast<unsigned short*>(&h);
}
__device__ __forceinline__ float bf2f(unsigned short u) {
    unsigned int v = (unsigned int)u << 16;
    return __uint_as_float(v);
}
__device__ __forceinline__ void split_bf(float x, unsigned short& hi, unsigned short& lo) {
    hi = f2bf(x);
    lo = f2bf(x - bf2f(hi));
}
__device__ __forceinline__ bf16x8 pack8(unsigned int w0, unsigned int w1,
                                        unsigned int w2, unsigned int w3) {
    union { unsigned int u[4]; bf16x8 v; } t;
    t.u[0] = w0; t.u[1] = w1; t.u[2] = w2; t.u[3] = w3;
    return t.v;
}

#define WSLOT 16384   // 128*128 bf16 elements per weight slot (K=128 only)

// ---------------------------------------------------------------------------
// Weight prep (K=128 MLPs): f32 [128][128] -> bf16 hi/lo, transposed.
// ---------------------------------------------------------------------------
__global__ __launch_bounds__(256) void prep_weights_kernel(
    const float* __restrict__ msgW1, const float* __restrict__ msgW2,
    const float* __restrict__ denseW1, const float* __restrict__ denseW2,
    unsigned short* __restrict__ WB)
{
    int slot = blockIdx.y;
    int kind = slot / 3, conv = slot % 3;
    const float* base;
    switch (kind) {
        case 0: base = msgW1; break;
        case 1: base = msgW2; break;
        case 2: base = denseW1; break;
        default: base = denseW2; break;
    }
    const float* W = base + (size_t)conv * 128 * 128;
    int idx = blockIdx.x * 256 + threadIdx.x;
    if (idx >= 16384) return;
    int c = idx >> 7, k = idx & 127;
    float val = W[(size_t)k * 128 + c];
    unsigned short hi, lo;
    split_bf(val, hi, lo);
    WB[(size_t)(2 * slot) * WSLOT + idx]     = hi;
    WB[(size_t)(2 * slot + 1) * WSLOT + idx] = lo;
}

// ---------------------------------------------------------------------------
// CSR build: histogram -> single-block scan with PER-NODE PADDING to x32.
// ---------------------------------------------------------------------------
__global__ __launch_bounds__(256) void hist_kernel(
    const int* __restrict__ nbr, int* __restrict__ counts, int E)
{
    int e = blockIdx.x * 256 + threadIdx.x;
    if (e < E) atomicAdd(&counts[nbr[2 * e]], 1);
}

__global__ __launch_bounds__(1024) void scan_kernel(
    const int* __restrict__ counts, int* __restrict__ peptr, int N)
{
    __shared__ int part[1024];
    const int t = threadIdx.x;
    const int chunk = DIV_UP(N, 1024);
    int s = 0;
    for (int c = 0; c < chunk; ++c) {
        int idx = t * chunk + c;
        if (idx < N) s += (counts[idx] + 31) & ~31;
    }
    part[t] = s;
    __syncthreads();
    for (int off = 1; off < 1024; off <<= 1) {
        int v = (t >= off) ? part[t - off] : 0;
        __syncthreads();
        part[t] += v;
        __syncthreads();
    }
    int pre = (t > 0) ? part[t - 1] : 0;
    for (int c = 0; c < chunk; ++c) {
        int idx = t * chunk + c;
        if (idx < N) { peptr[idx] = pre; pre += (counts[idx] + 31) & ~31; }
    }
    if (t == 1023) peptr[N] = part[1023];
}

// ---------------------------------------------------------------------------
// Fused edge geometry + padded-CSR scatter, CONTIGUOUS 32B records:
// only TWO scattered uint4 stores per edge (minimum line transactions).
// Record: rbfT[p*16 + k] = rbf value k (env-premultiplied bf16).
// envs (bf16) and js at padded positions; pad slots pre-zeroed by memset.
// ---------------------------------------------------------------------------
__global__ __launch_bounds__(256) void geom_scatter_kernel(
    const int* __restrict__ nbr, const float* __restrict__ xyz,
    const int* __restrict__ peptr, int* __restrict__ cursor,
    unsigned short* __restrict__ rbfT, unsigned short* __restrict__ envs,
    int* __restrict__ js, int E)
{
    int e = blockIdx.x * 256 + threadIdx.x;
    if (e >= E) return;
    int i = nbr[2 * e], j = nbr[2 * e + 1];
    float dx = xyz[3 * j + 0] - xyz[3 * i + 0];
    float dy = xyz[3 * j + 1] - xyz[3 * i + 1];
    float dz = xyz[3 * j + 2] - xyz[3 * i + 2];
    float dist = sqrtf(dx * dx + dy * dy + dz * dz);
    float x = dist * 0.3141592653589793f;   // pi/CUTOFF
    float s, c;
    __sincosf(x, &s, &c);
    float env = (dist < 10.0f) ? 0.5f * (c + 1.0f) : 0.0f;
    float inv_env = env / dist;
    float two_c = 2.0f * c;
    float sm1 = 0.0f, s0 = s;
    __align__(16) unsigned short ob[16];
    #pragma unroll
    for (int k = 0; k < 16; ++k) {
        ob[k] = f2bf(s0 * inv_env);
        float s1 = two_c * s0 - sm1;
        sm1 = s0; s0 = s1;
    }
    int p = peptr[i] + atomicAdd(&cursor[i], 1);
    uint4* rp = (uint4*)(rbfT + (size_t)p * 16);
    rp[0] = *(const uint4*)&ob[0];
    rp[1] = *(const uint4*)&ob[8];
    envs[p] = f2bf(env);
    js[p] = j;
}

// ---------------------------------------------------------------------------
// S0 = concat(S[N,124], res_embed[cg_z][N,4])  -> [N,128]
// ---------------------------------------------------------------------------
__global__ __launch_bounds__(256) void concat_s_kernel(
    const float* __restrict__ S, const float* __restrict__ res_embed,
    const int* __restrict__ z, float* __restrict__ S0, int N)
{
    int idx = blockIdx.x * 256 + threadIdx.x;
    if (idx >= N * 128) return;
    int n = idx >> 7, c = idx & 127;
    float val = (c < 124) ? S[n * 124 + c] : res_embed[z[n] * 4 + (c - 124)];
    S0[idx] = val;
}

// ---------------------------------------------------------------------------
// Split-bf16 MFMA two-stage MLP, K=128, LDS 56 KB (r6-proven).
// ---------------------------------------------------------------------------
template<int MT, bool PREACT, bool RESID, typename OutT>
__global__ __launch_bounds__(256) void mlp2_mfma_kernel(
    const float* __restrict__ X,
    const unsigned short* __restrict__ W1hi, const unsigned short* __restrict__ W1lo,
    const float* __restrict__ b1,
    const unsigned short* __restrict__ W2hi, const unsigned short* __restrict__ W2lo,
    const float* __restrict__ b2,
    OutT* __restrict__ Y, int nrows)
{
    constexpr int RB   = MT / 16;
    constexpr int ROWB = 256;
    __shared__ __align__(16) unsigned short XHhi[MT * 128];
    __shared__ __align__(16) unsigned short XHlo[MT * 128];
    __shared__ __align__(16) unsigned short WS[128 * 128];

    const int tid  = threadIdx.x;
    const int wave = tid >> 6;
    const int lane = tid & 63;
    const int l15  = lane & 15;
    const int kg   = lane >> 4;
    const int row0 = blockIdx.x * MT;

    for (int idx = tid; idx < MT * 32; idx += 256) {
        int r = idx >> 5, q = idx & 31;
        int gr = row0 + r;
        float4 xv = make_float4(0.f, 0.f, 0.f, 0.f);
        if (gr < nrows) xv = *(const float4*)(X + (size_t)gr * 128 + 4 * q);
        if (PREACT) { xv.x = silu_f(xv.x); xv.y = silu_f(xv.y);
                      xv.z = silu_f(xv.z); xv.w = silu_f(xv.w); }
        ushort4 h, l;
        split_bf(xv.x, h.x, l.x); split_bf(xv.y, h.y, l.y);
        split_bf(xv.z, h.z, l.z); split_bf(xv.w, h.w, l.w);
        int off = (8 * q) ^ ((r & 7) << 4);
        *(ushort4*)((char*)XHhi + r * ROWB + off) = h;
        *(ushort4*)((char*)XHlo + r * ROWB + off) = l;
    }

    f32x4 acc[RB][2];

    #define STAGE_W(WPTR)                                                       \
        for (int idx = tid; idx < 2048; idx += 256) {                           \
            int r = idx >> 4;                                                   \
            int byt = (idx & 15) * 16;                                          \
            *(uint4*)((char*)WS + r * ROWB + (byt ^ ((r & 7) << 4))) =          \
                *(const uint4*)((WPTR) + (size_t)idx * 8);                      \
        }

    #define PASS(WITH_LO)                                                       \
        _Pragma("unroll")                                                       \
        for (int kk = 0; kk < 4; ++kk) {                                        \
            const int kbyte = kk * 64 + kg * 16;                                \
            bf16x8 ah[RB], al[RB];                                              \
            _Pragma("unroll")                                                   \
            for (int rb = 0; rb < RB; ++rb) {                                   \
                int r = 16 * rb + l15;                                          \
                int off = kbyte ^ ((r & 7) << 4);                               \
                ah[rb] = *(const bf16x8*)((const char*)XHhi + r * ROWB + off);  \
                if (WITH_LO)                                                    \
                    al[rb] = *(const bf16x8*)((const char*)XHlo + r * ROWB + off); \
            }                                                                   \
            _Pragma("unroll")                                                   \
            for (int cbi = 0; cbi < 2; ++cbi) {                                 \
                int rw = 16 * (wave + 4 * cbi) + l15;                           \
                int offw = kbyte ^ ((rw & 7) << 4);                             \
                bf16x8 bw = *(const bf16x8*)((const char*)WS + rw * ROWB + offw); \
                _Pragma("unroll")                                               \
                for (int rb = 0; rb < RB; ++rb) {                               \
                    f32x4 t = acc[rb][cbi];                                     \
                    t = __builtin_amdgcn_mfma_f32_16x16x32_bf16(ah[rb], bw, t, 0, 0, 0); \
                    if (WITH_LO)                                                \
                        t = __builtin_amdgcn_mfma_f32_16x16x32_bf16(al[rb], bw, t, 0, 0, 0); \
                    acc[rb][cbi] = t;                                           \
                }                                                               \
            }                                                                   \
        }

    #pragma unroll
    for (int a = 0; a < RB; ++a) { acc[a][0] = (f32x4){0,0,0,0}; acc[a][1] = (f32x4){0,0,0,0}; }
    STAGE_W(W1hi)
    __syncthreads();
    PASS(true)
    __syncthreads();
    STAGE_W(W1lo)
    __syncthreads();
    PASS(false)
    __syncthreads();

    #pragma unroll
    for (int cbi = 0; cbi < 2; ++cbi) {
        int col = 16 * (wave + 4 * cbi) + l15;
        float b1v = b1[col];
        #pragma unroll
        for (int rb = 0; rb < RB; ++rb)
            #pragma unroll
            for (int i = 0; i < 4; ++i) {
                int r = 16 * rb + kg * 4 + i;
                float h = silu_f(acc[rb][cbi][i] + b1v);
                unsigned short hh, hl;
                split_bf(h, hh, hl);
                int off = (2 * col) ^ ((r & 7) << 4);
                *(unsigned short*)((char*)XHhi + r * ROWB + off) = hh;
                *(unsigned short*)((char*)XHlo + r * ROWB + off) = hl;
            }
    }
    #pragma unroll
    for (int a = 0; a < RB; ++a) { acc[a][0] = (f32x4){0,0,0,0}; acc[a][1] = (f32x4){0,0,0,0}; }
    STAGE_W(W2hi)
    __syncthreads();
    PASS(true)
    __syncthreads();
    STAGE_W(W2lo)
    __syncthreads();
    PASS(false)
    #undef PASS
    #undef STAGE_W

    #pragma unroll
    for (int cbi = 0; cbi < 2; ++cbi) {
        int col = 16 * (wave + 4 * cbi) + l15;
        float b2v = b2[col];
        #pragma unroll
        for (int rb = 0; rb < RB; ++rb)
            #pragma unroll
            for (int i = 0; i < 4; ++i) {
                int gr = row0 + 16 * rb + kg * 4 + i;
                if (gr < nrows) {
                    size_t off = (size_t)gr * 128 + col;
                    float val = acc[rb][cbi][i] + b2v;
                    if (RESID) val += (float)Y[off];
                    if constexpr (sizeof(OutT) == 2)
                        Y[off] = __float2bfloat16(val);
                    else
                        Y[off] = val;
                }
            }
    }
}

// ---------------------------------------------------------------------------
// Generic two-stage fp32 MLP, ROWS/RR template params + k-loop UNROLL 6.
// ---------------------------------------------------------------------------
template<int K, int ROWS, int RR, bool PREACT, bool RESID, typename OutT>
__global__ __launch_bounds__(256) void mlp2_kernel(
    const float* __restrict__ X, int ldX,
    const float* __restrict__ W1, const float* __restrict__ b1,
    const float* __restrict__ W2, const float* __restrict__ b2,
    OutT* __restrict__ Y, int ldY, int nrows)
{
    constexpr int NC = (K + 31) / 32;
    __shared__ float Xs[ROWS * K];
    __shared__ float Hs[ROWS * K];
    const int tid = threadIdx.x;
    const int row0 = blockIdx.x * ROWS;

    for (int idx = tid; idx < ROWS * K; idx += 256) {
        int r = idx / K, c = idx - r * K;
        int gr = row0 + r;
        float x = (gr < nrows) ? X[(size_t)gr * ldX + c] : 0.0f;
        if (PREACT) x = silu_f(x);
        Xs[idx] = x;
    }
    __syncthreads();

    const int cc = tid & 31;
    const int r0 = (tid >> 5) * RR;

    float acc[NC][RR];
    #pragma unroll
    for (int jc = 0; jc < NC; ++jc) {
        int col = cc + 32 * jc;
        float bv = (col < K) ? b1[col] : 0.0f;
        #pragma unroll
        for (int rr = 0; rr < RR; ++rr) acc[jc][rr] = bv;
    }
    #pragma unroll 6
    for (int k = 0; k < K; ++k) {
        float w[NC];
        #pragma unroll
        for (int jc = 0; jc < NC; ++jc) {
            int col = cc + 32 * jc;
            w[jc] = (col < K) ? W1[k * K + col] : 0.0f;
        }
        float xv[RR];
        #pragma unroll
        for (int rr = 0; rr < RR; ++rr) xv[rr] = Xs[(r0 + rr) * K + k];
        #pragma unroll
        for (int jc = 0; jc < NC; ++jc)
            #pragma unroll
            for (int rr = 0; rr < RR; ++rr)
                acc[jc][rr] = fmaf(xv[rr], w[jc], acc[jc][rr]);
    }
    #pragma unroll
    for (int jc = 0; jc < NC; ++jc) {
        int col = cc + 32 * jc;
        if (col < K) {
            #pragma unroll
            for (int rr = 0; rr < RR; ++rr)
                Hs[(r0 + rr) * K + col] = silu_f(acc[jc][rr]);
        }
    }
    __syncthreads();

    #pragma unroll
    for (int jc = 0; jc < NC; ++jc) {
        int col = cc + 32 * jc;
        float bv = (col < K) ? b2[col] : 0.0f;
        #pragma unroll
        for (int rr = 0; rr < RR; ++rr) acc[jc][rr] = bv;
    }
    #pragma unroll 6
    for (int k = 0; k < K; ++k) {
        float w[NC];
        #pragma unroll
        for (int jc = 0; jc < NC; ++jc) {
            int col = cc + 32 * jc;
            w[jc] = (col < K) ? W2[k * K + col] : 0.0f;
        }
        float xv[RR];
        #pragma unroll
        for (int rr = 0; rr < RR; ++rr) xv[rr] = Hs[(r0 + rr) * K + k];
        #pragma unroll
        for (int jc = 0; jc < NC; ++jc)
            #pragma unroll
            for (int rr = 0; rr < RR; ++rr)
                acc[jc][rr] = fmaf(xv[rr], w[jc], acc[jc][rr]);
    }
    #pragma unroll
    for (int jc = 0; jc < NC; ++jc) {
        int col = cc + 32 * jc;
        if (col < K) {
            #pragma unroll
            for (int rr = 0; rr < RR; ++rr) {
                int gr = row0 + r0 + rr;
                if (gr < nrows) {
                    size_t off = (size_t)gr * ldY + col;
                    float val = acc[jc][rr];
                    if (RESID) val += (float)Y[off];
                    if constexpr (sizeof(OutT) == 2)
                        Y[off] = __float2bfloat16(val);
                    else
                        Y[off] = val;
                }
            }
        }
    }
}

// ---------------------------------------------------------------------------
// Register-direct MFMA gather, COLUMN-SPLIT; A-frag from contiguous records
// via 8 scalar u16 loads (r8-proven addressing; pads zeroed, no masking).
// ---------------------------------------------------------------------------
__global__ __launch_bounds__(256) void gather_mfma_kernel(
    const int* __restrict__ peptr,
    const unsigned short* __restrict__ rbfT,   // [EPAD][16] contiguous records
    const unsigned short* __restrict__ envs,   // [EPAD] bf16 (pads zero)
    const int* __restrict__ js,                // [EPAD]      (pads zero)
    const unsigned short* __restrict__ phi,    // [N][128] bf16
    const float* __restrict__ distW, const float* __restrict__ distb,
    float* __restrict__ v, int N)
{
    const int wv = blockIdx.x * 4 + (threadIdx.x >> 6);
    const int lane = threadIdx.x & 63;
    const int n = wv >> 1;
    const int h = wv & 1;               // column half: cols 64h .. 64h+63
    if (n >= N) return;
    const int l15 = lane & 15;
    const int lg  = lane >> 4;

    f32x4 acc[4];
    float eac[4];
    #pragma unroll
    for (int cb = 0; cb < 4; ++cb) { acc[cb] = (f32x4){0,0,0,0}; eac[cb] = 0.f; }

    const int p0 = peptr[n], p1 = peptr[n + 1];

    for (int p = p0; p < p1; p += 32) {
        // A-frag: af[i] = rbfT[(p+8lg+i)*16 + l15], 8 scalar u16 loads
        // spanning 256B (2-3 lines, L2-hot).
        const unsigned short* ab = rbfT + (size_t)(p + 8 * lg) * 16 + l15;
        bf16x8 af = pack8(
            (unsigned int)ab[0]  | ((unsigned int)ab[16] << 16),
            (unsigned int)ab[32] | ((unsigned int)ab[48] << 16),
            (unsigned int)ab[64] | ((unsigned int)ab[80] << 16),
            (unsigned int)ab[96] | ((unsigned int)ab[112] << 16));

        bf16x8 a2f = (bf16x8){0,0,0,0,0,0,0,0};
        if (l15 == 0)
            a2f = *(const bf16x8*)(envs + p + 8 * lg);

        int4 j03 = *(const int4*)(js + p + 8 * lg);
        int4 j47 = *(const int4*)(js + p + 8 * lg + 4);

        const unsigned short* pb0 = phi + (size_t)j03.x * 128 + 64 * h + l15;
        const unsigned short* pb1 = phi + (size_t)j03.y * 128 + 64 * h + l15;
        const unsigned short* pb2 = phi + (size_t)j03.z * 128 + 64 * h + l15;
        const unsigned short* pb3 = phi + (size_t)j03.w * 128 + 64 * h + l15;
        const unsigned short* pb4 = phi + (size_t)j47.x * 128 + 64 * h + l15;
        const unsigned short* pb5 = phi + (size_t)j47.y * 128 + 64 * h + l15;
        const unsigned short* pb6 = phi + (size_t)j47.z * 128 + 64 * h + l15;
        const unsigned short* pb7 = phi + (size_t)j47.w * 128 + 64 * h + l15;

        #pragma unroll
        for (int cbi = 0; cbi < 4; ++cbi) {
            const int o = cbi * 16;
            unsigned int b0 = (unsigned int)pb0[o] | ((unsigned int)pb1[o] << 16);
            unsigned int b1 = (unsigned int)pb2[o] | ((unsigned int)pb3[o] << 16);
            unsigned int b2 = (unsigned int)pb4[o] | ((unsigned int)pb5[o] << 16);
            unsigned int b3 = (unsigned int)pb6[o] | ((unsigned int)pb7[o] << 16);
            bf16x8 bf = pack8(b0, b1, b2, b3);
            acc[cbi] = __builtin_amdgcn_mfma_f32_16x16x32_bf16(af, bf, acc[cbi], 0, 0, 0);
            f32x4 z = (f32x4){0, 0, 0, 0};
            z = __builtin_amdgcn_mfma_f32_16x16x32_bf16(a2f, bf, z, 0, 0, 0);
            eac[cbi] += z[0];
        }
    }

    #pragma unroll
    for (int cbi = 0; cbi < 4; ++cbi) {
        int col = 64 * h + cbi * 16 + l15;
        float part = acc[cbi][0] * distW[(lg * 4 + 0) * 128 + col];
        part = fmaf(acc[cbi][1], distW[(lg * 4 + 1) * 128 + col], part);
        part = fmaf(acc[cbi][2], distW[(lg * 4 + 2) * 128 + col], part);
        part = fmaf(acc[cbi][3], distW[(lg * 4 + 3) * 128 + col], part);
        if (lg == 0) part = fmaf(eac[cbi], distb[col], part);
        part += __shfl_xor(part, 16, 64);
        part += __shfl_xor(part, 32, 64);
        if (lane < 16) v[(size_t)n * 128 + col] = part;
    }
}

// ---------------------------------------------------------------------------
// Fused heads (r12-proven): bbA, bbT, scA, scS per node in one wave.
// ---------------------------------------------------------------------------
__global__ __launch_bounds__(256) void fused_heads_kernel(
    const float* __restrict__ S0,
    const float* __restrict__ bbaW1, const float* __restrict__ bbab1,
    const float* __restrict__ bbaW2, const float* __restrict__ bbab2,
    const float* __restrict__ bbtW1, const float* __restrict__ bbtb1,
    const float* __restrict__ bbtW2, const float* __restrict__ bbtb2,
    const float* __restrict__ scaW1, const float* __restrict__ scab1,
    const float* __restrict__ scaW2, const float* __restrict__ scab2,
    float* __restrict__ bbA, float* __restrict__ bbT,
    float* __restrict__ scA, float* __restrict__ scS, int N)
{
    const int wid = threadIdx.x >> 6;
    const int lane = threadIdx.x & 63;
    const int n = blockIdx.x * 4 + wid;
    if (n >= N) return;

    float x0 = S0[(size_t)n * 128 + lane];
    float x1 = S0[(size_t)n * 128 + 64 + lane];
    float s0 = silu_f(x0), s1 = silu_f(x1);

    // ---- bba (M=3, K=128) ----
    float ba[3];
    #pragma unroll
    for (int m = 0; m < 3; ++m)
        ba[m] = fmaf(s0, bbaW1[lane * 3 + m], s1 * bbaW1[(lane + 64) * 3 + m]);
    #pragma unroll
    for (int m = 0; m < 3; ++m)
        #pragma unroll
        for (int off = 32; off > 0; off >>= 1)
            ba[m] += __shfl_xor(ba[m], off, 64);
    float bbo[3];
    {
        float tm[3];
        #pragma unroll
        for (int m = 0; m < 3; ++m) tm[m] = silu_f(ba[m] + bbab1[m]);
        #pragma unroll
        for (int mm = 0; mm < 3; ++mm) {
            float o = bbab2[mm];
            #pragma unroll
            for (int m = 0; m < 3; ++m) o = fmaf(tm[m], bbaW2[m * 3 + mm], o);
            bbo[mm] = o;
        }
    }
    if (lane < 3) {
        float ov = bbo[0];
        if (lane == 1) ov = bbo[1];
        if (lane == 2) ov = bbo[2];
        bbA[(size_t)n * 3 + lane] = ov;
    }

    // ---- bbt (M=3, K=131 = S0 ++ bbA) ----
    float bt[3];
    #pragma unroll
    for (int m = 0; m < 3; ++m)
        bt[m] = fmaf(s0, bbtW1[lane * 3 + m], s1 * bbtW1[(lane + 64) * 3 + m]);
    #pragma unroll
    for (int m = 0; m < 3; ++m)
        #pragma unroll
        for (int off = 32; off > 0; off >>= 1)
            bt[m] += __shfl_xor(bt[m], off, 64);
    #pragma unroll
    for (int m = 0; m < 3; ++m)
        #pragma unroll
        for (int t = 0; t < 3; ++t)
            bt[m] = fmaf(silu_f(bbo[t]), bbtW1[(128 + t) * 3 + m], bt[m]);
    {
        float tm[3], bto[3];
        #pragma unroll
        for (int m = 0; m < 3; ++m) tm[m] = silu_f(bt[m] + bbtb1[m]);
        #pragma unroll
        for (int mm = 0; mm < 3; ++mm) {
            float o = bbtb2[mm];
            #pragma unroll
            for (int m = 0; m < 3; ++m) o = fmaf(tm[m], bbtW2[m * 3 + mm], o);
            bto[mm] = o;
        }
        if (lane < 3) {
            float ov = bto[0];
            if (lane == 1) ov = bto[1];
            if (lane == 2) ov = bto[2];
            bbT[(size_t)n * 3 + lane] = ov;
        }
    }

    // ---- sca (M=10, K=128) ----
    float sa[10];
    #pragma unroll
    for (int m = 0; m < 10; ++m)
        sa[m] = fmaf(s0, scaW1[lane * 10 + m], s1 * scaW1[(lane + 64) * 10 + m]);
    #pragma unroll
    for (int m = 0; m < 10; ++m)
        #pragma unroll
        for (int off = 32; off > 0; off >>= 1)
            sa[m] += __shfl_xor(sa[m], off, 64);
    float sco[10];
    {
        float tm[10];
        #pragma unroll
        for (int m = 0; m < 10; ++m) tm[m] = silu_f(sa[m] + scab1[m]);
        #pragma unroll
        for (int mm = 0; mm < 10; ++mm) {
            float o = scab2[mm];
            #pragma unroll
            for (int m = 0; m < 10; ++m) o = fmaf(tm[m], scaW2[m * 10 + mm], o);
            sco[mm] = o;
        }
    }
    float scv = sco[0];
    #pragma unroll
    for (int m = 1; m < 10; ++m)
        if (lane == m) scv = sco[m];
    if (lane < 10) scA[(size_t)n * 10 + lane] = scv;

    // ---- scS = concat(S0, scA, pad) ----
    scS[(size_t)n * 140 + lane] = x0;
    scS[(size_t)n * 140 + 64 + lane] = x1;
    if (lane < 12) scS[(size_t)n * 140 + 128 + lane] = (lane < 10) ? scv : 0.0f;
}

// ---------------------------------------------------------------------------
// Small head: out = silu( silu(x) @ W1 + b1 ) @ W2 + b2   (final linear)
// ---------------------------------------------------------------------------
template<int M>
__global__ __launch_bounds__(256) void head_kernel(
    const float* __restrict__ X, int ldX, int K1,
    const float* __restrict__ X2, int ldX2, int K2,
    const float* __restrict__ W1, const float* __restrict__ b1,
    const float* __restrict__ W2, const float* __restrict__ b2,
    float* __restrict__ out, int ldOut, int nrows)
{
    const int wid = threadIdx.x >> 6;
    const int lane = threadIdx.x & 63;
    const int n = blockIdx.x * 4 + wid;
    if (n >= nrows) return;
    const int K = K1 + K2;
    float sx[3];
    #pragma unroll
    for (int t = 0; t < 3; ++t) {
        int k = lane + 64 * t;
        float v = 0.0f;
        if (k < K1) v = X[(size_t)n * ldX + k];
        else if (k < K) v = X2[(size_t)n * ldX2 + (k - K1)];
        sx[t] = (k < K) ? silu_f(v) : 0.0f;
    }
    float acc[M];
    #pragma unroll
    for (int m = 0; m < M; ++m) {
        float a = 0.0f;
        #pragma unroll
        for (int t = 0; t < 3; ++t) {
            int k = lane + 64 * t;
            if (k < K) a = fmaf(sx[t], W1[k * M + m], a);
        }
        acc[m] = a;
    }
    #pragma unroll
    for (int m = 0; m < M; ++m) {
        #pragma unroll
        for (int off = 32; off > 0; off >>= 1)
            acc[m] += __shfl_xor(acc[m], off, 64);
    }
    float tm[M];
    #pragma unroll
    for (int m = 0; m < M; ++m) tm[m] = silu_f(acc[m] + b1[m]);
    if (lane < M) {
        float o = b2[lane];
        #pragma unroll
        for (int m = 0; m < M; ++m) o = fmaf(tm[m], W2[m * M + lane], o);
        out[(size_t)n * ldOut + lane] = o;
    }
}

// ---------------------------------------------------------------------------
// Output assembly: out[N][13][3]
// ---------------------------------------------------------------------------
__global__ __launch_bounds__(256) void assemble_kernel(
    const int* __restrict__ z,
    const float* __restrict__ bbde, const float* __restrict__ scde,
    const float* __restrict__ bbA, const float* __restrict__ bbT,
    const float* __restrict__ scA, const float* __restrict__ scT,
    float* __restrict__ out, int N)
{
    int idx = blockIdx.x * 256 + threadIdx.x;
    if (idx >= N * 39) return;
    int n = idx / 39;
    int s = idx - n * 39;
    int row = s / 3;
    int col = s - row * 3;
    float val;
    if (row < 3) {
        if (col == 0)      val = bbde[z[n] * 3 + row];
        else if (col == 1) val = bbA[n * 3 + row];
        else               val = bbT[n * 3 + row];
    } else {
        int r = row - 3;
        if (col == 0)      val = scde[z[n] * 10 + r];
        else if (col == 1) val = scA[n * 10 + r];
        else               val = scT[n * 10 + r];
    }
    out[idx] = val;
}

extern "C" void kernel_launch(void* const* d_in, const int* in_sizes, int n_in,
                              void* d_out, int out_size, void* d_ws, size_t ws_size,
                              hipStream_t stream)
{
    const int*   cg_z        = (const int*)d_in[0];
    const float* cg_xyz      = (const float*)d_in[1];
    const int*   nbr         = (const int*)d_in[2];
    // d_in[3] = mapping (unused by reference)
    const float* S_in        = (const float*)d_in[4];
    const float* res_embed   = (const float*)d_in[5];
    const float* msg_W1      = (const float*)d_in[6];
    const float* msg_b1      = (const float*)d_in[7];
    const float* msg_W2      = (const float*)d_in[8];
    const float* msg_b2      = (const float*)d_in[9];
    const float* dist_W      = (const float*)d_in[10];
    const float* dist_b      = (const float*)d_in[11];
    const float* dense_W1    = (const float*)d_in[12];
    const float* dense_b1    = (const float*)d_in[13];
    const float* dense_W2    = (const float*)d_in[14];
    const float* dense_b2    = (const float*)d_in[15];
    const float* bb_dist_emb = (const float*)d_in[16];
    const float* sc_dist_emb = (const float*)d_in[17];
    const float* bba_W1      = (const float*)d_in[18];
    const float* bba_b1      = (const float*)d_in[19];
    const float* bba_W2      = (const float*)d_in[20];
    const float* bba_b2      = (const float*)d_in[21];
    const float* sca_W1      = (const float*)d_in[22];
    const float* sca_b1      = (const float*)d_in[23];
    const float* sca_W2      = (const float*)d_in[24];
    const float* sca_b2      = (const float*)d_in[25];
    const float* bbt_W1      = (const float*)d_in[26];
    const float* bbt_b1      = (const float*)d_in[27];
    const float* bbt_W2      = (const float*)d_in[28];
    const float* bbt_b2      = (const float*)d_in[29];
    const float* sct_W1      = (const float*)d_in[30];
    const float* sct_b1      = (const float*)d_in[31];
    const float* sct_W2      = (const float*)d_in[32];
    const float* sct_b2      = (const float*)d_in[33];
    const float* ft_W1       = (const float*)d_in[34];
    const float* ft_b1       = (const float*)d_in[35];
    const float* ft_W2       = (const float*)d_in[36];
    const float* ft_b2       = (const float*)d_in[37];

    const int N = in_sizes[0];
    const int E = in_sizes[2] / 2;
    const int EPAD = ((E + 31 * N) / 32) * 32 + 32;   // padded-edge upper bound

    unsigned short* WB   = (unsigned short*)d_ws;                      // 24*WSLOT
    unsigned short* rbfT = WB + (size_t)24 * WSLOT;                    // EPAD*16 (contiguous records)
    unsigned short* envs = rbfT + (size_t)EPAD * 16;                   // EPAD
    int*            js   = (int*)(envs + (size_t)EPAD);                // EPAD
    float* ws   = (float*)(js + (size_t)EPAD);
    float* S0   = ws;  ws += (size_t)N * 128;
    float* V    = ws;  ws += (size_t)N * 128;
    float* scS  = ws;  ws += (size_t)N * 140;
    float* bbA  = ws;  ws += (size_t)N * 3;
    float* bbT  = ws;  ws += (size_t)N * 3;
    float* scA  = ws;  ws += (size_t)N * 10;
    float* scT  = ws;  ws += (size_t)N * 10;
    __hip_bfloat16* PHI = (__hip_bfloat16*)ws;  ws += (size_t)N * 64;  // N*128 bf16
    int* peptr  = (int*)ws;  ws = (float*)((int*)ws + (N + 1));
    int* counts = (int*)ws;  ws = (float*)((int*)ws + N);
    int* cursor = (int*)ws;  ws = (float*)((int*)ws + N);

    // Zero padded edge region (rbfT|envs|js contiguous) + counts/cursor.
    (void)hipMemsetAsync(rbfT, 0, (size_t)EPAD * 38, stream);
    (void)hipMemsetAsync(counts, 0, (size_t)2 * N * sizeof(int), stream);

    prep_weights_kernel<<<dim3(64, 12), 256, 0, stream>>>(
        msg_W1, msg_W2, dense_W1, dense_W2, WB);

    hist_kernel<<<DIV_UP(E, 256), 256, 0, stream>>>(nbr, counts, E);
    scan_kernel<<<1, 1024, 0, stream>>>(counts, peptr, N);
    geom_scatter_kernel<<<DIV_UP(E, 256), 256, 0, stream>>>(
        nbr, cg_xyz, peptr, cursor, rbfT, envs, js, E);

    concat_s_kernel<<<DIV_UP(N * 128, 256), 256, 0, stream>>>(S_in, res_embed, cg_z, S0, N);

    #define WHI(kind, conv) (WB + (size_t)(2 * ((kind) * 3 + (conv))) * WSLOT)
    #define WLO(kind, conv) (WB + (size_t)(2 * ((kind) * 3 + (conv)) + 1) * WSLOT)

    for (int i = 0; i < 3; ++i) {
        mlp2_mfma_kernel<48, false, false, __hip_bfloat16>
            <<<DIV_UP(N, 48), 256, 0, stream>>>(
            S0, WHI(0, i), WLO(0, i), msg_b1 + i * 128,
            WHI(1, i), WLO(1, i), msg_b2 + i * 128, PHI, N);
        gather_mfma_kernel<<<DIV_UP(2 * N, 4), 256, 0, stream>>>(
            peptr, rbfT, envs, js, (const unsigned short*)PHI,
            dist_W + (size_t)i * 16 * 128, dist_b + i * 128, V, N);
        mlp2_mfma_kernel<48, true, true, float>
            <<<DIV_UP(N, 48), 256, 0, stream>>>(
            V, WHI(2, i), WLO(2, i), dense_b1 + i * 128,
            WHI(3, i), WLO(3, i), dense_b2 + i * 128, S0, N);
    }

    fused_heads_kernel<<<DIV_UP(N, 4), 256, 0, stream>>>(
        S0,
        bba_W1, bba_b1, bba_W2, bba_b2,
        bbt_W1, bbt_b1, bbt_W2, bbt_b2,
        sca_W1, sca_b1, sca_W2, sca_b2,
        bbA, bbT, scA, scS, N);

    for (int i = 0; i < 3; ++i) {
        mlp2_kernel<138, 16, 2, true, true, float><<<DIV_UP(N, 16), 256, 0, stream>>>(
            scS, 140, sct_W1 + (size_t)i * 138 * 138, sct_b1 + i * 138,
            sct_W2 + (size_t)i * 138 * 138, sct_b2 + i * 138, scS, 140, N);
    }
    head_kernel<10><<<DIV_UP(N, 4), 256, 0, stream>>>(
        scS, 140, 138, scS, 0, 0, ft_W1, ft_b1, ft_W2, ft_b2, scT, 10, N);

    assemble_kernel<<<DIV_UP(N * 39, 256), 256, 0, stream>>>(
        cg_z, bb_dist_emb, sc_dist_emb, bbA, bbT, scA, scT, (float*)d_out, N);

    #undef WHI
    #undef WLO
}

// Round 19
// 605.041 us; speedup vs baseline: 1.1034x; 1.0530x over previous
//
#include <hip/hip_runtime.h>
#include <hip/hip_bf16.h>

#define DIV_UP(a,b) (((a)+(b)-1)/(b))

typedef __attribute__((ext_vector_type(8))) short bf16x8;
typedef __attribute__((ext_vector_type(4))) float f32x4;

__device__ __forceinline__ float silu_f(float x) {
    return x / (1.0f + __expf(-x));
}
__device__ __forceinline__ unsigned short f2bf(float x) {
    __hip_bfloat16 h = __float2bfloat16(x);
    return *reinterpret_cast<unsigned short*>(&h);
}
__device__ __forceinline__ float bf2f(unsigned short u) {
    unsigned int v = (unsigned int)u << 16;
    return __uint_as_float(v);
}
__device__ __forceinline__ void split_bf(float x, unsigned short& hi, unsigned short& lo) {
    hi = f2bf(x);
    lo = f2bf(x - bf2f(hi));
}
__device__ __forceinline__ bf16x8 pack8(unsigned int w0, unsigned int w1,
                                        unsigned int w2, unsigned int w3) {
    union { unsigned int u[4]; bf16x8 v; } t;
    t.u[0] = w0; t.u[1] = w1; t.u[2] = w2; t.u[3] = w3;
    return t.v;
}

#define WSLOT 16384   // 128*128 bf16 elements per weight slot (K=128 only)

// ---------------------------------------------------------------------------
// Weight prep (K=128 MLPs): f32 [128][128] -> bf16 hi/lo, transposed.
// ---------------------------------------------------------------------------
__global__ __launch_bounds__(256) void prep_weights_kernel(
    const float* __restrict__ msgW1, const float* __restrict__ msgW2,
    const float* __restrict__ denseW1, const float* __restrict__ denseW2,
    unsigned short* __restrict__ WB)
{
    int slot = blockIdx.y;
    int kind = slot / 3, conv = slot % 3;
    const float* base;
    switch (kind) {
        case 0: base = msgW1; break;
        case 1: base = msgW2; break;
        case 2: base = denseW1; break;
        default: base = denseW2; break;
    }
    const float* W = base + (size_t)conv * 128 * 128;
    int idx = blockIdx.x * 256 + threadIdx.x;
    if (idx >= 16384) return;
    int c = idx >> 7, k = idx & 127;
    float val = W[(size_t)k * 128 + c];
    unsigned short hi, lo;
    split_bf(val, hi, lo);
    WB[(size_t)(2 * slot) * WSLOT + idx]     = hi;
    WB[(size_t)(2 * slot + 1) * WSLOT + idx] = lo;
}

// ---------------------------------------------------------------------------
// CSR build: histogram -> single-block scan with PER-NODE PADDING to x32.
// ---------------------------------------------------------------------------
__global__ __launch_bounds__(256) void hist_kernel(
    const int* __restrict__ nbr, int* __restrict__ counts, int E)
{
    int e = blockIdx.x * 256 + threadIdx.x;
    if (e < E) atomicAdd(&counts[nbr[2 * e]], 1);
}

__global__ __launch_bounds__(1024) void scan_kernel(
    const int* __restrict__ counts, int* __restrict__ peptr, int N)
{
    __shared__ int part[1024];
    const int t = threadIdx.x;
    const int chunk = DIV_UP(N, 1024);
    int s = 0;
    for (int c = 0; c < chunk; ++c) {
        int idx = t * chunk + c;
        if (idx < N) s += (counts[idx] + 31) & ~31;
    }
    part[t] = s;
    __syncthreads();
    for (int off = 1; off < 1024; off <<= 1) {
        int v = (t >= off) ? part[t - off] : 0;
        __syncthreads();
        part[t] += v;
        __syncthreads();
    }
    int pre = (t > 0) ? part[t - 1] : 0;
    for (int c = 0; c < chunk; ++c) {
        int idx = t * chunk + c;
        if (idx < N) { peptr[idx] = pre; pre += (counts[idx] + 31) & ~31; }
    }
    if (t == 1023) peptr[N] = part[1023];
}

// ---------------------------------------------------------------------------
// Fused edge geometry + padded-CSR scatter, CONTIGUOUS 32B records:
// only TWO scattered uint4 stores per edge (minimum line transactions).
// ---------------------------------------------------------------------------
__global__ __launch_bounds__(256) void geom_scatter_kernel(
    const int* __restrict__ nbr, const float* __restrict__ xyz,
    const int* __restrict__ peptr, int* __restrict__ cursor,
    unsigned short* __restrict__ rbfT, unsigned short* __restrict__ envs,
    int* __restrict__ js, int E)
{
    int e = blockIdx.x * 256 + threadIdx.x;
    if (e >= E) return;
    int i = nbr[2 * e], j = nbr[2 * e + 1];
    float dx = xyz[3 * j + 0] - xyz[3 * i + 0];
    float dy = xyz[3 * j + 1] - xyz[3 * i + 1];
    float dz = xyz[3 * j + 2] - xyz[3 * i + 2];
    float dist = sqrtf(dx * dx + dy * dy + dz * dz);
    float x = dist * 0.3141592653589793f;   // pi/CUTOFF
    float s, c;
    __sincosf(x, &s, &c);
    float env = (dist < 10.0f) ? 0.5f * (c + 1.0f) : 0.0f;
    float inv_env = env / dist;
    float two_c = 2.0f * c;
    float sm1 = 0.0f, s0 = s;
    __align__(16) unsigned short ob[16];
    #pragma unroll
    for (int k = 0; k < 16; ++k) {
        ob[k] = f2bf(s0 * inv_env);
        float s1 = two_c * s0 - sm1;
        sm1 = s0; s0 = s1;
    }
    int p = peptr[i] + atomicAdd(&cursor[i], 1);
    uint4* rp = (uint4*)(rbfT + (size_t)p * 16);
    rp[0] = *(const uint4*)&ob[0];
    rp[1] = *(const uint4*)&ob[8];
    envs[p] = f2bf(env);
    js[p] = j;
}

// ---------------------------------------------------------------------------
// S0 = concat(S[N,124], res_embed[cg_z][N,4])  -> [N,128]
// ---------------------------------------------------------------------------
__global__ __launch_bounds__(256) void concat_s_kernel(
    const float* __restrict__ S, const float* __restrict__ res_embed,
    const int* __restrict__ z, float* __restrict__ S0, int N)
{
    int idx = blockIdx.x * 256 + threadIdx.x;
    if (idx >= N * 128) return;
    int n = idx >> 7, c = idx & 127;
    float val = (c < 124) ? S[n * 124 + c] : res_embed[z[n] * 4 + (c - 124)];
    S0[idx] = val;
}

// ---------------------------------------------------------------------------
// Split-bf16 MFMA two-stage MLP, K=128, LDS 56 KB (r6-proven).
// ---------------------------------------------------------------------------
template<int MT, bool PREACT, bool RESID, typename OutT>
__global__ __launch_bounds__(256) void mlp2_mfma_kernel(
    const float* __restrict__ X,
    const unsigned short* __restrict__ W1hi, const unsigned short* __restrict__ W1lo,
    const float* __restrict__ b1,
    const unsigned short* __restrict__ W2hi, const unsigned short* __restrict__ W2lo,
    const float* __restrict__ b2,
    OutT* __restrict__ Y, int nrows)
{
    constexpr int RB   = MT / 16;
    constexpr int ROWB = 256;
    __shared__ __align__(16) unsigned short XHhi[MT * 128];
    __shared__ __align__(16) unsigned short XHlo[MT * 128];
    __shared__ __align__(16) unsigned short WS[128 * 128];

    const int tid  = threadIdx.x;
    const int wave = tid >> 6;
    const int lane = tid & 63;
    const int l15  = lane & 15;
    const int kg   = lane >> 4;
    const int row0 = blockIdx.x * MT;

    for (int idx = tid; idx < MT * 32; idx += 256) {
        int r = idx >> 5, q = idx & 31;
        int gr = row0 + r;
        float4 xv = make_float4(0.f, 0.f, 0.f, 0.f);
        if (gr < nrows) xv = *(const float4*)(X + (size_t)gr * 128 + 4 * q);
        if (PREACT) { xv.x = silu_f(xv.x); xv.y = silu_f(xv.y);
                      xv.z = silu_f(xv.z); xv.w = silu_f(xv.w); }
        ushort4 h, l;
        split_bf(xv.x, h.x, l.x); split_bf(xv.y, h.y, l.y);
        split_bf(xv.z, h.z, l.z); split_bf(xv.w, h.w, l.w);
        int off = (8 * q) ^ ((r & 7) << 4);
        *(ushort4*)((char*)XHhi + r * ROWB + off) = h;
        *(ushort4*)((char*)XHlo + r * ROWB + off) = l;
    }

    f32x4 acc[RB][2];

    #define STAGE_W(WPTR)                                                       \
        for (int idx = tid; idx < 2048; idx += 256) {                           \
            int r = idx >> 4;                                                   \
            int byt = (idx & 15) * 16;                                          \
            *(uint4*)((char*)WS + r * ROWB + (byt ^ ((r & 7) << 4))) =          \
                *(const uint4*)((WPTR) + (size_t)idx * 8);                      \
        }

    #define PASS(WITH_LO)                                                       \
        _Pragma("unroll")                                                       \
        for (int kk = 0; kk < 4; ++kk) {                                        \
            const int kbyte = kk * 64 + kg * 16;                                \
            bf16x8 ah[RB], al[RB];                                              \
            _Pragma("unroll")                                                   \
            for (int rb = 0; rb < RB; ++rb) {                                   \
                int r = 16 * rb + l15;                                          \
                int off = kbyte ^ ((r & 7) << 4);                               \
                ah[rb] = *(const bf16x8*)((const char*)XHhi + r * ROWB + off);  \
                if (WITH_LO)                                                    \
                    al[rb] = *(const bf16x8*)((const char*)XHlo + r * ROWB + off); \
            }                                                                   \
            _Pragma("unroll")                                                   \
            for (int cbi = 0; cbi < 2; ++cbi) {                                 \
                int rw = 16 * (wave + 4 * cbi) + l15;                           \
                int offw = kbyte ^ ((rw & 7) << 4);                             \
                bf16x8 bw = *(const bf16x8*)((const char*)WS + rw * ROWB + offw); \
                _Pragma("unroll")                                               \
                for (int rb = 0; rb < RB; ++rb) {                               \
                    f32x4 t = acc[rb][cbi];                                     \
                    t = __builtin_amdgcn_mfma_f32_16x16x32_bf16(ah[rb], bw, t, 0, 0, 0); \
                    if (WITH_LO)                                                \
                        t = __builtin_amdgcn_mfma_f32_16x16x32_bf16(al[rb], bw, t, 0, 0, 0); \
                    acc[rb][cbi] = t;                                           \
                }                                                               \
            }                                                                   \
        }

    #pragma unroll
    for (int a = 0; a < RB; ++a) { acc[a][0] = (f32x4){0,0,0,0}; acc[a][1] = (f32x4){0,0,0,0}; }
    STAGE_W(W1hi)
    __syncthreads();
    PASS(true)
    __syncthreads();
    STAGE_W(W1lo)
    __syncthreads();
    PASS(false)
    __syncthreads();

    #pragma unroll
    for (int cbi = 0; cbi < 2; ++cbi) {
        int col = 16 * (wave + 4 * cbi) + l15;
        float b1v = b1[col];
        #pragma unroll
        for (int rb = 0; rb < RB; ++rb)
            #pragma unroll
            for (int i = 0; i < 4; ++i) {
                int r = 16 * rb + kg * 4 + i;
                float h = silu_f(acc[rb][cbi][i] + b1v);
                unsigned short hh, hl;
                split_bf(h, hh, hl);
                int off = (2 * col) ^ ((r & 7) << 4);
                *(unsigned short*)((char*)XHhi + r * ROWB + off) = hh;
                *(unsigned short*)((char*)XHlo + r * ROWB + off) = hl;
            }
    }
    #pragma unroll
    for (int a = 0; a < RB; ++a) { acc[a][0] = (f32x4){0,0,0,0}; acc[a][1] = (f32x4){0,0,0,0}; }
    STAGE_W(W2hi)
    __syncthreads();
    PASS(true)
    __syncthreads();
    STAGE_W(W2lo)
    __syncthreads();
    PASS(false)
    #undef PASS
    #undef STAGE_W

    #pragma unroll
    for (int cbi = 0; cbi < 2; ++cbi) {
        int col = 16 * (wave + 4 * cbi) + l15;
        float b2v = b2[col];
        #pragma unroll
        for (int rb = 0; rb < RB; ++rb)
            #pragma unroll
            for (int i = 0; i < 4; ++i) {
                int gr = row0 + 16 * rb + kg * 4 + i;
                if (gr < nrows) {
                    size_t off = (size_t)gr * 128 + col;
                    float val = acc[rb][cbi][i] + b2v;
                    if (RESID) val += (float)Y[off];
                    if constexpr (sizeof(OutT) == 2)
                        Y[off] = __float2bfloat16(val);
                    else
                        Y[off] = val;
                }
            }
    }
}

// ---------------------------------------------------------------------------
// FUSED sct stack: 3 residual MLP layers (K=138) + ft head, rows persistent
// in LDS (Raw/Xs/Hs ping-pong, 26.5 KB).  Only scT is written to global.
// Inner k-loops use the r16-proven unroll-6 pattern.
// ---------------------------------------------------------------------------
__global__ __launch_bounds__(256) void sct_fused_kernel(
    const float* __restrict__ scS,
    const float* __restrict__ sctW1, const float* __restrict__ sctb1,
    const float* __restrict__ sctW2, const float* __restrict__ sctb2,
    const float* __restrict__ ftW1, const float* __restrict__ ftb1,
    const float* __restrict__ ftW2, const float* __restrict__ ftb2,
    float* __restrict__ scT, int nrows)
{
    constexpr int K = 138, ROWS = 16, RR = 2, NC = 5;
    __shared__ float Raw[ROWS * K];
    __shared__ float Xs[ROWS * K];
    __shared__ float Hs[ROWS * K];
    const int tid = threadIdx.x;
    const int row0 = blockIdx.x * ROWS;
    const int cc = tid & 31;
    const int r0 = (tid >> 5) * RR;

    for (int idx = tid; idx < ROWS * K; idx += 256) {
        int r = idx / K, c = idx - r * K;
        int gr = row0 + r;
        Raw[idx] = (gr < nrows) ? scS[(size_t)gr * 140 + c] : 0.0f;
    }

    float acc[NC][RR];

    for (int layer = 0; layer < 3; ++layer) {
        const float* W1 = sctW1 + (size_t)layer * K * K;
        const float* b1 = sctb1 + layer * K;
        const float* W2 = sctW2 + (size_t)layer * K * K;
        const float* b2 = sctb2 + layer * K;

        __syncthreads();                       // Raw ready (stage or prev layer)
        for (int idx = tid; idx < ROWS * K; idx += 256)
            Xs[idx] = silu_f(Raw[idx]);
        __syncthreads();

        // ---- stage 1: Hs = silu(Xs @ W1 + b1) ----
        #pragma unroll
        for (int jc = 0; jc < NC; ++jc) {
            int col = cc + 32 * jc;
            float bv = (col < K) ? b1[col] : 0.0f;
            #pragma unroll
            for (int rr = 0; rr < RR; ++rr) acc[jc][rr] = bv;
        }
        #pragma unroll 6
        for (int k = 0; k < K; ++k) {
            float w[NC];
            #pragma unroll
            for (int jc = 0; jc < NC; ++jc) {
                int col = cc + 32 * jc;
                w[jc] = (col < K) ? W1[k * K + col] : 0.0f;
            }
            float xv[RR];
            #pragma unroll
            for (int rr = 0; rr < RR; ++rr) xv[rr] = Xs[(r0 + rr) * K + k];
            #pragma unroll
            for (int jc = 0; jc < NC; ++jc)
                #pragma unroll
                for (int rr = 0; rr < RR; ++rr)
                    acc[jc][rr] = fmaf(xv[rr], w[jc], acc[jc][rr]);
        }
        #pragma unroll
        for (int jc = 0; jc < NC; ++jc) {
            int col = cc + 32 * jc;
            if (col < K) {
                #pragma unroll
                for (int rr = 0; rr < RR; ++rr)
                    Hs[(r0 + rr) * K + col] = silu_f(acc[jc][rr]);
            }
        }
        __syncthreads();

        // ---- stage 2: Raw += Hs @ W2 + b2 ----
        #pragma unroll
        for (int jc = 0; jc < NC; ++jc) {
            int col = cc + 32 * jc;
            float bv = (col < K) ? b2[col] : 0.0f;
            #pragma unroll
            for (int rr = 0; rr < RR; ++rr) acc[jc][rr] = bv;
        }
        #pragma unroll 6
        for (int k = 0; k < K; ++k) {
            float w[NC];
            #pragma unroll
            for (int jc = 0; jc < NC; ++jc) {
                int col = cc + 32 * jc;
                w[jc] = (col < K) ? W2[k * K + col] : 0.0f;
            }
            float xv[RR];
            #pragma unroll
            for (int rr = 0; rr < RR; ++rr) xv[rr] = Hs[(r0 + rr) * K + k];
            #pragma unroll
            for (int jc = 0; jc < NC; ++jc)
                #pragma unroll
                for (int rr = 0; rr < RR; ++rr)
                    acc[jc][rr] = fmaf(xv[rr], w[jc], acc[jc][rr]);
        }
        #pragma unroll
        for (int jc = 0; jc < NC; ++jc) {
            int col = cc + 32 * jc;
            if (col < K) {
                #pragma unroll
                for (int rr = 0; rr < RR; ++rr)
                    Raw[(r0 + rr) * K + col] += acc[jc][rr];   // thread-owned
            }
        }
    }
    __syncthreads();

    // ---- ft head: 16 lanes per row, shfl-reduce over the 16-lane group ----
    {
        const int r  = tid >> 4;     // 0..15 (4 rows per wave, group-aligned)
        const int kl = tid & 15;
        const int gr = row0 + r;
        float a[10];
        #pragma unroll
        for (int m = 0; m < 10; ++m) a[m] = 0.0f;
        for (int k = kl; k < K; k += 16) {
            float xv = silu_f(Raw[r * K + k]);
            #pragma unroll
            for (int m = 0; m < 10; ++m)
                a[m] = fmaf(xv, ftW1[k * 10 + m], a[m]);
        }
        #pragma unroll
        for (int m = 0; m < 10; ++m) {
            a[m] += __shfl_xor(a[m], 1, 64);
            a[m] += __shfl_xor(a[m], 2, 64);
            a[m] += __shfl_xor(a[m], 4, 64);
            a[m] += __shfl_xor(a[m], 8, 64);
        }
        float tm[10];
        #pragma unroll
        for (int m = 0; m < 10; ++m) tm[m] = silu_f(a[m] + ftb1[m]);
        if (kl < 10 && gr < nrows) {
            float o = ftb2[kl];
            #pragma unroll
            for (int m = 0; m < 10; ++m) o = fmaf(tm[m], ftW2[m * 10 + kl], o);
            scT[(size_t)gr * 10 + kl] = o;
        }
    }
}

// ---------------------------------------------------------------------------
// Register-direct MFMA gather, COLUMN-SPLIT; A-frag via 8 scalar u16 loads.
// ---------------------------------------------------------------------------
__global__ __launch_bounds__(256) void gather_mfma_kernel(
    const int* __restrict__ peptr,
    const unsigned short* __restrict__ rbfT,   // [EPAD][16] contiguous records
    const unsigned short* __restrict__ envs,   // [EPAD] bf16 (pads zero)
    const int* __restrict__ js,                // [EPAD]      (pads zero)
    const unsigned short* __restrict__ phi,    // [N][128] bf16
    const float* __restrict__ distW, const float* __restrict__ distb,
    float* __restrict__ v, int N)
{
    const int wv = blockIdx.x * 4 + (threadIdx.x >> 6);
    const int lane = threadIdx.x & 63;
    const int n = wv >> 1;
    const int h = wv & 1;               // column half: cols 64h .. 64h+63
    if (n >= N) return;
    const int l15 = lane & 15;
    const int lg  = lane >> 4;

    f32x4 acc[4];
    float eac[4];
    #pragma unroll
    for (int cb = 0; cb < 4; ++cb) { acc[cb] = (f32x4){0,0,0,0}; eac[cb] = 0.f; }

    const int p0 = peptr[n], p1 = peptr[n + 1];

    for (int p = p0; p < p1; p += 32) {
        const unsigned short* ab = rbfT + (size_t)(p + 8 * lg) * 16 + l15;
        bf16x8 af = pack8(
            (unsigned int)ab[0]  | ((unsigned int)ab[16] << 16),
            (unsigned int)ab[32] | ((unsigned int)ab[48] << 16),
            (unsigned int)ab[64] | ((unsigned int)ab[80] << 16),
            (unsigned int)ab[96] | ((unsigned int)ab[112] << 16));

        bf16x8 a2f = (bf16x8){0,0,0,0,0,0,0,0};
        if (l15 == 0)
            a2f = *(const bf16x8*)(envs + p + 8 * lg);

        int4 j03 = *(const int4*)(js + p + 8 * lg);
        int4 j47 = *(const int4*)(js + p + 8 * lg + 4);

        const unsigned short* pb0 = phi + (size_t)j03.x * 128 + 64 * h + l15;
        const unsigned short* pb1 = phi + (size_t)j03.y * 128 + 64 * h + l15;
        const unsigned short* pb2 = phi + (size_t)j03.z * 128 + 64 * h + l15;
        const unsigned short* pb3 = phi + (size_t)j03.w * 128 + 64 * h + l15;
        const unsigned short* pb4 = phi + (size_t)j47.x * 128 + 64 * h + l15;
        const unsigned short* pb5 = phi + (size_t)j47.y * 128 + 64 * h + l15;
        const unsigned short* pb6 = phi + (size_t)j47.z * 128 + 64 * h + l15;
        const unsigned short* pb7 = phi + (size_t)j47.w * 128 + 64 * h + l15;

        #pragma unroll
        for (int cbi = 0; cbi < 4; ++cbi) {
            const int o = cbi * 16;
            unsigned int b0 = (unsigned int)pb0[o] | ((unsigned int)pb1[o] << 16);
            unsigned int b1 = (unsigned int)pb2[o] | ((unsigned int)pb3[o] << 16);
            unsigned int b2 = (unsigned int)pb4[o] | ((unsigned int)pb5[o] << 16);
            unsigned int b3 = (unsigned int)pb6[o] | ((unsigned int)pb7[o] << 16);
            bf16x8 bf = pack8(b0, b1, b2, b3);
            acc[cbi] = __builtin_amdgcn_mfma_f32_16x16x32_bf16(af, bf, acc[cbi], 0, 0, 0);
            f32x4 z = (f32x4){0, 0, 0, 0};
            z = __builtin_amdgcn_mfma_f32_16x16x32_bf16(a2f, bf, z, 0, 0, 0);
            eac[cbi] += z[0];
        }
    }

    #pragma unroll
    for (int cbi = 0; cbi < 4; ++cbi) {
        int col = 64 * h + cbi * 16 + l15;
        float part = acc[cbi][0] * distW[(lg * 4 + 0) * 128 + col];
        part = fmaf(acc[cbi][1], distW[(lg * 4 + 1) * 128 + col], part);
        part = fmaf(acc[cbi][2], distW[(lg * 4 + 2) * 128 + col], part);
        part = fmaf(acc[cbi][3], distW[(lg * 4 + 3) * 128 + col], part);
        if (lg == 0) part = fmaf(eac[cbi], distb[col], part);
        part += __shfl_xor(part, 16, 64);
        part += __shfl_xor(part, 32, 64);
        if (lane < 16) v[(size_t)n * 128 + col] = part;
    }
}

// ---------------------------------------------------------------------------
// Fused heads (r12-proven): bbA, bbT, scA, scS per node in one wave.
// ---------------------------------------------------------------------------
__global__ __launch_bounds__(256) void fused_heads_kernel(
    const float* __restrict__ S0,
    const float* __restrict__ bbaW1, const float* __restrict__ bbab1,
    const float* __restrict__ bbaW2, const float* __restrict__ bbab2,
    const float* __restrict__ bbtW1, const float* __restrict__ bbtb1,
    const float* __restrict__ bbtW2, const float* __restrict__ bbtb2,
    const float* __restrict__ scaW1, const float* __restrict__ scab1,
    const float* __restrict__ scaW2, const float* __restrict__ scab2,
    float* __restrict__ bbA, float* __restrict__ bbT,
    float* __restrict__ scA, float* __restrict__ scS, int N)
{
    const int wid = threadIdx.x >> 6;
    const int lane = threadIdx.x & 63;
    const int n = blockIdx.x * 4 + wid;
    if (n >= N) return;

    float x0 = S0[(size_t)n * 128 + lane];
    float x1 = S0[(size_t)n * 128 + 64 + lane];
    float s0 = silu_f(x0), s1 = silu_f(x1);

    // ---- bba (M=3, K=128) ----
    float ba[3];
    #pragma unroll
    for (int m = 0; m < 3; ++m)
        ba[m] = fmaf(s0, bbaW1[lane * 3 + m], s1 * bbaW1[(lane + 64) * 3 + m]);
    #pragma unroll
    for (int m = 0; m < 3; ++m)
        #pragma unroll
        for (int off = 32; off > 0; off >>= 1)
            ba[m] += __shfl_xor(ba[m], off, 64);
    float bbo[3];
    {
        float tm[3];
        #pragma unroll
        for (int m = 0; m < 3; ++m) tm[m] = silu_f(ba[m] + bbab1[m]);
        #pragma unroll
        for (int mm = 0; mm < 3; ++mm) {
            float o = bbab2[mm];
            #pragma unroll
            for (int m = 0; m < 3; ++m) o = fmaf(tm[m], bbaW2[m * 3 + mm], o);
            bbo[mm] = o;
        }
    }
    if (lane < 3) {
        float ov = bbo[0];
        if (lane == 1) ov = bbo[1];
        if (lane == 2) ov = bbo[2];
        bbA[(size_t)n * 3 + lane] = ov;
    }

    // ---- bbt (M=3, K=131 = S0 ++ bbA) ----
    float bt[3];
    #pragma unroll
    for (int m = 0; m < 3; ++m)
        bt[m] = fmaf(s0, bbtW1[lane * 3 + m], s1 * bbtW1[(lane + 64) * 3 + m]);
    #pragma unroll
    for (int m = 0; m < 3; ++m)
        #pragma unroll
        for (int off = 32; off > 0; off >>= 1)
            bt[m] += __shfl_xor(bt[m], off, 64);
    #pragma unroll
    for (int m = 0; m < 3; ++m)
        #pragma unroll
        for (int t = 0; t < 3; ++t)
            bt[m] = fmaf(silu_f(bbo[t]), bbtW1[(128 + t) * 3 + m], bt[m]);
    {
        float tm[3], bto[3];
        #pragma unroll
        for (int m = 0; m < 3; ++m) tm[m] = silu_f(bt[m] + bbtb1[m]);
        #pragma unroll
        for (int mm = 0; mm < 3; ++mm) {
            float o = bbtb2[mm];
            #pragma unroll
            for (int m = 0; m < 3; ++m) o = fmaf(tm[m], bbtW2[m * 3 + mm], o);
            bto[mm] = o;
        }
        if (lane < 3) {
            float ov = bto[0];
            if (lane == 1) ov = bto[1];
            if (lane == 2) ov = bto[2];
            bbT[(size_t)n * 3 + lane] = ov;
        }
    }

    // ---- sca (M=10, K=128) ----
    float sa[10];
    #pragma unroll
    for (int m = 0; m < 10; ++m)
        sa[m] = fmaf(s0, scaW1[lane * 10 + m], s1 * scaW1[(lane + 64) * 10 + m]);
    #pragma unroll
    for (int m = 0; m < 10; ++m)
        #pragma unroll
        for (int off = 32; off > 0; off >>= 1)
            sa[m] += __shfl_xor(sa[m], off, 64);
    float sco[10];
    {
        float tm[10];
        #pragma unroll
        for (int m = 0; m < 10; ++m) tm[m] = silu_f(sa[m] + scab1[m]);
        #pragma unroll
        for (int mm = 0; mm < 10; ++mm) {
            float o = scab2[mm];
            #pragma unroll
            for (int m = 0; m < 10; ++m) o = fmaf(tm[m], scaW2[m * 10 + mm], o);
            sco[mm] = o;
        }
    }
    float scv = sco[0];
    #pragma unroll
    for (int m = 1; m < 10; ++m)
        if (lane == m) scv = sco[m];
    if (lane < 10) scA[(size_t)n * 10 + lane] = scv;

    // ---- scS = concat(S0, scA, pad) ----
    scS[(size_t)n * 140 + lane] = x0;
    scS[(size_t)n * 140 + 64 + lane] = x1;
    if (lane < 12) scS[(size_t)n * 140 + 128 + lane] = (lane < 10) ? scv : 0.0f;
}

// ---------------------------------------------------------------------------
// Output assembly: out[N][13][3]
// ---------------------------------------------------------------------------
__global__ __launch_bounds__(256) void assemble_kernel(
    const int* __restrict__ z,
    const float* __restrict__ bbde, const float* __restrict__ scde,
    const float* __restrict__ bbA, const float* __restrict__ bbT,
    const float* __restrict__ scA, const float* __restrict__ scT,
    float* __restrict__ out, int N)
{
    int idx = blockIdx.x * 256 + threadIdx.x;
    if (idx >= N * 39) return;
    int n = idx / 39;
    int s = idx - n * 39;
    int row = s / 3;
    int col = s - row * 3;
    float val;
    if (row < 3) {
        if (col == 0)      val = bbde[z[n] * 3 + row];
        else if (col == 1) val = bbA[n * 3 + row];
        else               val = bbT[n * 3 + row];
    } else {
        int r = row - 3;
        if (col == 0)      val = scde[z[n] * 10 + r];
        else if (col == 1) val = scA[n * 10 + r];
        else               val = scT[n * 10 + r];
    }
    out[idx] = val;
}

extern "C" void kernel_launch(void* const* d_in, const int* in_sizes, int n_in,
                              void* d_out, int out_size, void* d_ws, size_t ws_size,
                              hipStream_t stream)
{
    const int*   cg_z        = (const int*)d_in[0];
    const float* cg_xyz      = (const float*)d_in[1];
    const int*   nbr         = (const int*)d_in[2];
    // d_in[3] = mapping (unused by reference)
    const float* S_in        = (const float*)d_in[4];
    const float* res_embed   = (const float*)d_in[5];
    const float* msg_W1      = (const float*)d_in[6];
    const float* msg_b1      = (const float*)d_in[7];
    const float* msg_W2      = (const float*)d_in[8];
    const float* msg_b2      = (const float*)d_in[9];
    const float* dist_W      = (const float*)d_in[10];
    const float* dist_b      = (const float*)d_in[11];
    const float* dense_W1    = (const float*)d_in[12];
    const float* dense_b1    = (const float*)d_in[13];
    const float* dense_W2    = (const float*)d_in[14];
    const float* dense_b2    = (const float*)d_in[15];
    const float* bb_dist_emb = (const float*)d_in[16];
    const float* sc_dist_emb = (const float*)d_in[17];
    const float* bba_W1      = (const float*)d_in[18];
    const float* bba_b1      = (const float*)d_in[19];
    const float* bba_W2      = (const float*)d_in[20];
    const float* bba_b2      = (const float*)d_in[21];
    const float* sca_W1      = (const float*)d_in[22];
    const float* sca_b1      = (const float*)d_in[23];
    const float* sca_W2      = (const float*)d_in[24];
    const float* sca_b2      = (const float*)d_in[25];
    const float* bbt_W1      = (const float*)d_in[26];
    const float* bbt_b1      = (const float*)d_in[27];
    const float* bbt_W2      = (const float*)d_in[28];
    const float* bbt_b2      = (const float*)d_in[29];
    const float* sct_W1      = (const float*)d_in[30];
    const float* sct_b1      = (const float*)d_in[31];
    const float* sct_W2      = (const float*)d_in[32];
    const float* sct_b2      = (const float*)d_in[33];
    const float* ft_W1       = (const float*)d_in[34];
    const float* ft_b1       = (const float*)d_in[35];
    const float* ft_W2       = (const float*)d_in[36];
    const float* ft_b2       = (const float*)d_in[37];

    const int N = in_sizes[0];
    const int E = in_sizes[2] / 2;
    const int EPAD = ((E + 31 * N) / 32) * 32 + 32;   // padded-edge upper bound

    unsigned short* WB   = (unsigned short*)d_ws;                      // 24*WSLOT
    unsigned short* rbfT = WB + (size_t)24 * WSLOT;                    // EPAD*16 (contiguous records)
    unsigned short* envs = rbfT + (size_t)EPAD * 16;                   // EPAD
    int*            js   = (int*)(envs + (size_t)EPAD);                // EPAD
    float* ws   = (float*)(js + (size_t)EPAD);
    float* S0   = ws;  ws += (size_t)N * 128;
    float* V    = ws;  ws += (size_t)N * 128;
    float* scS  = ws;  ws += (size_t)N * 140;
    float* bbA  = ws;  ws += (size_t)N * 3;
    float* bbT  = ws;  ws += (size_t)N * 3;
    float* scA  = ws;  ws += (size_t)N * 10;
    float* scT  = ws;  ws += (size_t)N * 10;
    __hip_bfloat16* PHI = (__hip_bfloat16*)ws;  ws += (size_t)N * 64;  // N*128 bf16
    int* peptr  = (int*)ws;  ws = (float*)((int*)ws + (N + 1));
    int* counts = (int*)ws;  ws = (float*)((int*)ws + N);
    int* cursor = (int*)ws;  ws = (float*)((int*)ws + N);

    // Zero padded edge region (rbfT|envs|js contiguous) + counts/cursor.
    (void)hipMemsetAsync(rbfT, 0, (size_t)EPAD * 38, stream);
    (void)hipMemsetAsync(counts, 0, (size_t)2 * N * sizeof(int), stream);

    prep_weights_kernel<<<dim3(64, 12), 256, 0, stream>>>(
        msg_W1, msg_W2, dense_W1, dense_W2, WB);

    hist_kernel<<<DIV_UP(E, 256), 256, 0, stream>>>(nbr, counts, E);
    scan_kernel<<<1, 1024, 0, stream>>>(counts, peptr, N);
    geom_scatter_kernel<<<DIV_UP(E, 256), 256, 0, stream>>>(
        nbr, cg_xyz, peptr, cursor, rbfT, envs, js, E);

    concat_s_kernel<<<DIV_UP(N * 128, 256), 256, 0, stream>>>(S_in, res_embed, cg_z, S0, N);

    #define WHI(kind, conv) (WB + (size_t)(2 * ((kind) * 3 + (conv))) * WSLOT)
    #define WLO(kind, conv) (WB + (size_t)(2 * ((kind) * 3 + (conv)) + 1) * WSLOT)

    for (int i = 0; i < 3; ++i) {
        mlp2_mfma_kernel<48, false, false, __hip_bfloat16>
            <<<DIV_UP(N, 48), 256, 0, stream>>>(
            S0, WHI(0, i), WLO(0, i), msg_b1 + i * 128,
            WHI(1, i), WLO(1, i), msg_b2 + i * 128, PHI, N);
        gather_mfma_kernel<<<DIV_UP(2 * N, 4), 256, 0, stream>>>(
            peptr, rbfT, envs, js, (const unsigned short*)PHI,
            dist_W + (size_t)i * 16 * 128, dist_b + i * 128, V, N);
        mlp2_mfma_kernel<48, true, true, float>
            <<<DIV_UP(N, 48), 256, 0, stream>>>(
            V, WHI(2, i), WLO(2, i), dense_b1 + i * 128,
            WHI(3, i), WLO(3, i), dense_b2 + i * 128, S0, N);
    }

    fused_heads_kernel<<<DIV_UP(N, 4), 256, 0, stream>>>(
        S0,
        bba_W1, bba_b1, bba_W2, bba_b2,
        bbt_W1, bbt_b1, bbt_W2, bbt_b2,
        sca_W1, sca_b1, sca_W2, sca_b2,
        bbA, bbT, scA, scS, N);

    sct_fused_kernel<<<DIV_UP(N, 16), 256, 0, stream>>>(
        scS, sct_W1, sct_b1, sct_W2, sct_b2,
        ft_W1, ft_b1, ft_W2, ft_b2, scT, N);

    assemble_kernel<<<DIV_UP(N * 39, 256), 256, 0, stream>>>(
        cg_z, bb_dist_emb, sc_dist_emb, bbA, bbT, scA, scT, (float*)d_out, N);

    #undef WHI
    #undef WLO
}

// Round 20
// 601.610 us; speedup vs baseline: 1.1097x; 1.0057x over previous
//
#include <hip/hip_runtime.h>
#include <hip/hip_bf16.h>

#define DIV_UP(a,b) (((a)+(b)-1)/(b))

typedef __attribute__((ext_vector_type(8))) short bf16x8;
typedef __attribute__((ext_vector_type(4))) float f32x4;

__device__ __forceinline__ float silu_f(float x) {
    return x / (1.0f + __expf(-x));
}
__device__ __forceinline__ unsigned short f2bf(float x) {
    __hip_bfloat16 h = __float2bfloat16(x);
    return *reinterpret_cast<unsigned short*>(&h);
}
__device__ __forceinline__ float bf2f(unsigned short u) {
    unsigned int v = (unsigned int)u << 16;
    return __uint_as_float(v);
}
__device__ __forceinline__ void split_bf(float x, unsigned short& hi, unsigned short& lo) {
    hi = f2bf(x);
    lo = f2bf(x - bf2f(hi));
}
__device__ __forceinline__ bf16x8 pack8(unsigned int w0, unsigned int w1,
                                        unsigned int w2, unsigned int w3) {
    union { unsigned int u[4]; bf16x8 v; } t;
    t.u[0] = w0; t.u[1] = w1; t.u[2] = w2; t.u[3] = w3;
    return t.v;
}

#define WSLOT 16384   // 128*128 bf16 elements per weight slot (K=128 only)

// ---------------------------------------------------------------------------
// Weight prep (K=128 MLPs): f32 [128][128] -> bf16 hi/lo, transposed.
// ---------------------------------------------------------------------------
__global__ __launch_bounds__(256) void prep_weights_kernel(
    const float* __restrict__ msgW1, const float* __restrict__ msgW2,
    const float* __restrict__ denseW1, const float* __restrict__ denseW2,
    unsigned short* __restrict__ WB)
{
    int slot = blockIdx.y;
    int kind = slot / 3, conv = slot % 3;
    const float* base;
    switch (kind) {
        case 0: base = msgW1; break;
        case 1: base = msgW2; break;
        case 2: base = denseW1; break;
        default: base = denseW2; break;
    }
    const float* W = base + (size_t)conv * 128 * 128;
    int idx = blockIdx.x * 256 + threadIdx.x;
    if (idx >= 16384) return;
    int c = idx >> 7, k = idx & 127;
    float val = W[(size_t)k * 128 + c];
    unsigned short hi, lo;
    split_bf(val, hi, lo);
    WB[(size_t)(2 * slot) * WSLOT + idx]     = hi;
    WB[(size_t)(2 * slot + 1) * WSLOT + idx] = lo;
}

// ---------------------------------------------------------------------------
// CSR build: histogram -> single-block scan with PER-NODE PADDING to x32.
// ---------------------------------------------------------------------------
__global__ __launch_bounds__(256) void hist_kernel(
    const int* __restrict__ nbr, int* __restrict__ counts, int E)
{
    int e = blockIdx.x * 256 + threadIdx.x;
    if (e < E) atomicAdd(&counts[nbr[2 * e]], 1);
}

__global__ __launch_bounds__(1024) void scan_kernel(
    const int* __restrict__ counts, int* __restrict__ peptr, int N)
{
    __shared__ int part[1024];
    const int t = threadIdx.x;
    const int chunk = DIV_UP(N, 1024);
    int s = 0;
    for (int c = 0; c < chunk; ++c) {
        int idx = t * chunk + c;
        if (idx < N) s += (counts[idx] + 31) & ~31;
    }
    part[t] = s;
    __syncthreads();
    for (int off = 1; off < 1024; off <<= 1) {
        int v = (t >= off) ? part[t - off] : 0;
        __syncthreads();
        part[t] += v;
        __syncthreads();
    }
    int pre = (t > 0) ? part[t - 1] : 0;
    for (int c = 0; c < chunk; ++c) {
        int idx = t * chunk + c;
        if (idx < N) { peptr[idx] = pre; pre += (counts[idx] + 31) & ~31; }
    }
    if (t == 1023) peptr[N] = part[1023];
}

// ---------------------------------------------------------------------------
// Fused edge geometry + padded-CSR scatter, CONTIGUOUS 32B records:
// only TWO scattered uint4 stores per edge (minimum line transactions).
// ---------------------------------------------------------------------------
__global__ __launch_bounds__(256) void geom_scatter_kernel(
    const int* __restrict__ nbr, const float* __restrict__ xyz,
    const int* __restrict__ peptr, int* __restrict__ cursor,
    unsigned short* __restrict__ rbfT, unsigned short* __restrict__ envs,
    int* __restrict__ js, int E)
{
    int e = blockIdx.x * 256 + threadIdx.x;
    if (e >= E) return;
    int i = nbr[2 * e], j = nbr[2 * e + 1];
    float dx = xyz[3 * j + 0] - xyz[3 * i + 0];
    float dy = xyz[3 * j + 1] - xyz[3 * i + 1];
    float dz = xyz[3 * j + 2] - xyz[3 * i + 2];
    float dist = sqrtf(dx * dx + dy * dy + dz * dz);
    float x = dist * 0.3141592653589793f;   // pi/CUTOFF
    float s, c;
    __sincosf(x, &s, &c);
    float env = (dist < 10.0f) ? 0.5f * (c + 1.0f) : 0.0f;
    float inv_env = env / dist;
    float two_c = 2.0f * c;
    float sm1 = 0.0f, s0 = s;
    __align__(16) unsigned short ob[16];
    #pragma unroll
    for (int k = 0; k < 16; ++k) {
        ob[k] = f2bf(s0 * inv_env);
        float s1 = two_c * s0 - sm1;
        sm1 = s0; s0 = s1;
    }
    int p = peptr[i] + atomicAdd(&cursor[i], 1);
    uint4* rp = (uint4*)(rbfT + (size_t)p * 16);
    rp[0] = *(const uint4*)&ob[0];
    rp[1] = *(const uint4*)&ob[8];
    envs[p] = f2bf(env);
    js[p] = j;
}

// ---------------------------------------------------------------------------
// S0 = concat(S[N,124], res_embed[cg_z][N,4])  -> [N,128]
// ---------------------------------------------------------------------------
__global__ __launch_bounds__(256) void concat_s_kernel(
    const float* __restrict__ S, const float* __restrict__ res_embed,
    const int* __restrict__ z, float* __restrict__ S0, int N)
{
    int idx = blockIdx.x * 256 + threadIdx.x;
    if (idx >= N * 128) return;
    int n = idx >> 7, c = idx & 127;
    float val = (c < 124) ? S[n * 124 + c] : res_embed[z[n] * 4 + (c - 124)];
    S0[idx] = val;
}

// ---------------------------------------------------------------------------
// Split-bf16 MFMA two-stage MLP, K=128, LDS 56 KB (r6-proven).
// ---------------------------------------------------------------------------
template<int MT, bool PREACT, bool RESID, typename OutT>
__global__ __launch_bounds__(256) void mlp2_mfma_kernel(
    const float* __restrict__ X,
    const unsigned short* __restrict__ W1hi, const unsigned short* __restrict__ W1lo,
    const float* __restrict__ b1,
    const unsigned short* __restrict__ W2hi, const unsigned short* __restrict__ W2lo,
    const float* __restrict__ b2,
    OutT* __restrict__ Y, int nrows)
{
    constexpr int RB   = MT / 16;
    constexpr int ROWB = 256;
    __shared__ __align__(16) unsigned short XHhi[MT * 128];
    __shared__ __align__(16) unsigned short XHlo[MT * 128];
    __shared__ __align__(16) unsigned short WS[128 * 128];

    const int tid  = threadIdx.x;
    const int wave = tid >> 6;
    const int lane = tid & 63;
    const int l15  = lane & 15;
    const int kg   = lane >> 4;
    const int row0 = blockIdx.x * MT;

    for (int idx = tid; idx < MT * 32; idx += 256) {
        int r = idx >> 5, q = idx & 31;
        int gr = row0 + r;
        float4 xv = make_float4(0.f, 0.f, 0.f, 0.f);
        if (gr < nrows) xv = *(const float4*)(X + (size_t)gr * 128 + 4 * q);
        if (PREACT) { xv.x = silu_f(xv.x); xv.y = silu_f(xv.y);
                      xv.z = silu_f(xv.z); xv.w = silu_f(xv.w); }
        ushort4 h, l;
        split_bf(xv.x, h.x, l.x); split_bf(xv.y, h.y, l.y);
        split_bf(xv.z, h.z, l.z); split_bf(xv.w, h.w, l.w);
        int off = (8 * q) ^ ((r & 7) << 4);
        *(ushort4*)((char*)XHhi + r * ROWB + off) = h;
        *(ushort4*)((char*)XHlo + r * ROWB + off) = l;
    }

    f32x4 acc[RB][2];

    #define STAGE_W(WPTR)                                                       \
        for (int idx = tid; idx < 2048; idx += 256) {                           \
            int r = idx >> 4;                                                   \
            int byt = (idx & 15) * 16;                                          \
            *(uint4*)((char*)WS + r * ROWB + (byt ^ ((r & 7) << 4))) =          \
                *(const uint4*)((WPTR) + (size_t)idx * 8);                      \
        }

    #define PASS(WITH_LO)                                                       \
        _Pragma("unroll")                                                       \
        for (int kk = 0; kk < 4; ++kk) {                                        \
            const int kbyte = kk * 64 + kg * 16;                                \
            bf16x8 ah[RB], al[RB];                                              \
            _Pragma("unroll")                                                   \
            for (int rb = 0; rb < RB; ++rb) {                                   \
                int r = 16 * rb + l15;                                          \
                int off = kbyte ^ ((r & 7) << 4);                               \
                ah[rb] = *(const bf16x8*)((const char*)XHhi + r * ROWB + off);  \
                if (WITH_LO)                                                    \
                    al[rb] = *(const bf16x8*)((const char*)XHlo + r * ROWB + off); \
            }                                                                   \
            _Pragma("unroll")                                                   \
            for (int cbi = 0; cbi < 2; ++cbi) {                                 \
                int rw = 16 * (wave + 4 * cbi) + l15;                           \
                int offw = kbyte ^ ((rw & 7) << 4);                             \
                bf16x8 bw = *(const bf16x8*)((const char*)WS + rw * ROWB + offw); \
                _Pragma("unroll")                                               \
                for (int rb = 0; rb < RB; ++rb) {                               \
                    f32x4 t = acc[rb][cbi];                                     \
                    t = __builtin_amdgcn_mfma_f32_16x16x32_bf16(ah[rb], bw, t, 0, 0, 0); \
                    if (WITH_LO)                                                \
                        t = __builtin_amdgcn_mfma_f32_16x16x32_bf16(al[rb], bw, t, 0, 0, 0); \
                    acc[rb][cbi] = t;                                           \
                }                                                               \
            }                                                                   \
        }

    #pragma unroll
    for (int a = 0; a < RB; ++a) { acc[a][0] = (f32x4){0,0,0,0}; acc[a][1] = (f32x4){0,0,0,0}; }
    STAGE_W(W1hi)
    __syncthreads();
    PASS(true)
    __syncthreads();
    STAGE_W(W1lo)
    __syncthreads();
    PASS(false)
    __syncthreads();

    #pragma unroll
    for (int cbi = 0; cbi < 2; ++cbi) {
        int col = 16 * (wave + 4 * cbi) + l15;
        float b1v = b1[col];
        #pragma unroll
        for (int rb = 0; rb < RB; ++rb)
            #pragma unroll
            for (int i = 0; i < 4; ++i) {
                int r = 16 * rb + kg * 4 + i;
                float h = silu_f(acc[rb][cbi][i] + b1v);
                unsigned short hh, hl;
                split_bf(h, hh, hl);
                int off = (2 * col) ^ ((r & 7) << 4);
                *(unsigned short*)((char*)XHhi + r * ROWB + off) = hh;
                *(unsigned short*)((char*)XHlo + r * ROWB + off) = hl;
            }
    }
    #pragma unroll
    for (int a = 0; a < RB; ++a) { acc[a][0] = (f32x4){0,0,0,0}; acc[a][1] = (f32x4){0,0,0,0}; }
    STAGE_W(W2hi)
    __syncthreads();
    PASS(true)
    __syncthreads();
    STAGE_W(W2lo)
    __syncthreads();
    PASS(false)
    #undef PASS
    #undef STAGE_W

    #pragma unroll
    for (int cbi = 0; cbi < 2; ++cbi) {
        int col = 16 * (wave + 4 * cbi) + l15;
        float b2v = b2[col];
        #pragma unroll
        for (int rb = 0; rb < RB; ++rb)
            #pragma unroll
            for (int i = 0; i < 4; ++i) {
                int gr = row0 + 16 * rb + kg * 4 + i;
                if (gr < nrows) {
                    size_t off = (size_t)gr * 128 + col;
                    float val = acc[rb][cbi][i] + b2v;
                    if (RESID) val += (float)Y[off];
                    if constexpr (sizeof(OutT) == 2)
                        Y[off] = __float2bfloat16(val);
                    else
                        Y[off] = val;
                }
            }
    }
}

// ---------------------------------------------------------------------------
// FUSED sct stack + OUTPUT ASSEMBLY: 3 residual MLP layers (K=138) + ft head,
// rows persistent in LDS; writes out[N][13][3] directly (bb from bbA/bbT/
// embeds, sc from scA/embeds + in-register sc_torsion).  k-loops unroll 12.
// ---------------------------------------------------------------------------
__global__ __launch_bounds__(256) void sct_fused_kernel(
    const float* __restrict__ scS,
    const float* __restrict__ sctW1, const float* __restrict__ sctb1,
    const float* __restrict__ sctW2, const float* __restrict__ sctb2,
    const float* __restrict__ ftW1, const float* __restrict__ ftb1,
    const float* __restrict__ ftW2, const float* __restrict__ ftb2,
    const int* __restrict__ cg_z,
    const float* __restrict__ bbde, const float* __restrict__ scde,
    const float* __restrict__ bbA, const float* __restrict__ bbT,
    const float* __restrict__ scA,
    float* __restrict__ out, int nrows)
{
    constexpr int K = 138, ROWS = 16, RR = 2, NC = 5;
    __shared__ float Raw[ROWS * K];
    __shared__ float Xs[ROWS * K];
    __shared__ float Hs[ROWS * K];
    const int tid = threadIdx.x;
    const int row0 = blockIdx.x * ROWS;
    const int cc = tid & 31;
    const int r0 = (tid >> 5) * RR;

    for (int idx = tid; idx < ROWS * K; idx += 256) {
        int r = idx / K, c = idx - r * K;
        int gr = row0 + r;
        Raw[idx] = (gr < nrows) ? scS[(size_t)gr * 140 + c] : 0.0f;
    }

    float acc[NC][RR];

    for (int layer = 0; layer < 3; ++layer) {
        const float* W1 = sctW1 + (size_t)layer * K * K;
        const float* b1 = sctb1 + layer * K;
        const float* W2 = sctW2 + (size_t)layer * K * K;
        const float* b2 = sctb2 + layer * K;

        __syncthreads();                       // Raw ready (stage or prev layer)
        for (int idx = tid; idx < ROWS * K; idx += 256)
            Xs[idx] = silu_f(Raw[idx]);
        __syncthreads();

        // ---- stage 1: Hs = silu(Xs @ W1 + b1) ----
        #pragma unroll
        for (int jc = 0; jc < NC; ++jc) {
            int col = cc + 32 * jc;
            float bv = (col < K) ? b1[col] : 0.0f;
            #pragma unroll
            for (int rr = 0; rr < RR; ++rr) acc[jc][rr] = bv;
        }
        #pragma unroll 12
        for (int k = 0; k < K; ++k) {
            float w[NC];
            #pragma unroll
            for (int jc = 0; jc < NC; ++jc) {
                int col = cc + 32 * jc;
                w[jc] = (col < K) ? W1[k * K + col] : 0.0f;
            }
            float xv[RR];
            #pragma unroll
            for (int rr = 0; rr < RR; ++rr) xv[rr] = Xs[(r0 + rr) * K + k];
            #pragma unroll
            for (int jc = 0; jc < NC; ++jc)
                #pragma unroll
                for (int rr = 0; rr < RR; ++rr)
                    acc[jc][rr] = fmaf(xv[rr], w[jc], acc[jc][rr]);
        }
        #pragma unroll
        for (int jc = 0; jc < NC; ++jc) {
            int col = cc + 32 * jc;
            if (col < K) {
                #pragma unroll
                for (int rr = 0; rr < RR; ++rr)
                    Hs[(r0 + rr) * K + col] = silu_f(acc[jc][rr]);
            }
        }
        __syncthreads();

        // ---- stage 2: Raw += Hs @ W2 + b2 ----
        #pragma unroll
        for (int jc = 0; jc < NC; ++jc) {
            int col = cc + 32 * jc;
            float bv = (col < K) ? b2[col] : 0.0f;
            #pragma unroll
            for (int rr = 0; rr < RR; ++rr) acc[jc][rr] = bv;
        }
        #pragma unroll 12
        for (int k = 0; k < K; ++k) {
            float w[NC];
            #pragma unroll
            for (int jc = 0; jc < NC; ++jc) {
                int col = cc + 32 * jc;
                w[jc] = (col < K) ? W2[k * K + col] : 0.0f;
            }
            float xv[RR];
            #pragma unroll
            for (int rr = 0; rr < RR; ++rr) xv[rr] = Hs[(r0 + rr) * K + k];
            #pragma unroll
            for (int jc = 0; jc < NC; ++jc)
                #pragma unroll
                for (int rr = 0; rr < RR; ++rr)
                    acc[jc][rr] = fmaf(xv[rr], w[jc], acc[jc][rr]);
        }
        #pragma unroll
        for (int jc = 0; jc < NC; ++jc) {
            int col = cc + 32 * jc;
            if (col < K) {
                #pragma unroll
                for (int rr = 0; rr < RR; ++rr)
                    Raw[(r0 + rr) * K + col] += acc[jc][rr];   // thread-owned
            }
        }
    }
    __syncthreads();

    // ---- ft head (16 lanes/row, shfl-reduce) + full output assembly ----
    {
        const int r  = tid >> 4;     // 0..15 (4 rows per wave, group-aligned)
        const int kl = tid & 15;
        const int gr = row0 + r;
        float a[10];
        #pragma unroll
        for (int m = 0; m < 10; ++m) a[m] = 0.0f;
        for (int k = kl; k < K; k += 16) {
            float xv = silu_f(Raw[r * K + k]);
            #pragma unroll
            for (int m = 0; m < 10; ++m)
                a[m] = fmaf(xv, ftW1[k * 10 + m], a[m]);
        }
        #pragma unroll
        for (int m = 0; m < 10; ++m) {
            a[m] += __shfl_xor(a[m], 1, 64);
            a[m] += __shfl_xor(a[m], 2, 64);
            a[m] += __shfl_xor(a[m], 4, 64);
            a[m] += __shfl_xor(a[m], 8, 64);
        }
        float tm[10];
        #pragma unroll
        for (int m = 0; m < 10; ++m) tm[m] = silu_f(a[m] + ftb1[m]);
        if (gr < nrows) {
            float* orow = out + (size_t)gr * 39;
            const int z = cg_z[gr];
            if (kl < 10) {
                float o = ftb2[kl];
                #pragma unroll
                for (int m = 0; m < 10; ++m) o = fmaf(tm[m], ftW2[m * 10 + kl], o);
                orow[9 + kl * 3 + 0] = scde[z * 10 + kl];
                orow[9 + kl * 3 + 1] = scA[(size_t)gr * 10 + kl];
                orow[9 + kl * 3 + 2] = o;
            }
            if (kl < 3) {
                orow[kl * 3 + 0] = bbde[z * 3 + kl];
                orow[kl * 3 + 1] = bbA[(size_t)gr * 3 + kl];
                orow[kl * 3 + 2] = bbT[(size_t)gr * 3 + kl];
            }
        }
    }
}

// ---------------------------------------------------------------------------
// Register-direct MFMA gather, COLUMN-SPLIT; A-frag via 8 scalar u16 loads.
// ---------------------------------------------------------------------------
__global__ __launch_bounds__(256) void gather_mfma_kernel(
    const int* __restrict__ peptr,
    const unsigned short* __restrict__ rbfT,   // [EPAD][16] contiguous records
    const unsigned short* __restrict__ envs,   // [EPAD] bf16 (pads zero)
    const int* __restrict__ js,                // [EPAD]      (pads zero)
    const unsigned short* __restrict__ phi,    // [N][128] bf16
    const float* __restrict__ distW, const float* __restrict__ distb,
    float* __restrict__ v, int N)
{
    const int wv = blockIdx.x * 4 + (threadIdx.x >> 6);
    const int lane = threadIdx.x & 63;
    const int n = wv >> 1;
    const int h = wv & 1;               // column half: cols 64h .. 64h+63
    if (n >= N) return;
    const int l15 = lane & 15;
    const int lg  = lane >> 4;

    f32x4 acc[4];
    float eac[4];
    #pragma unroll
    for (int cb = 0; cb < 4; ++cb) { acc[cb] = (f32x4){0,0,0,0}; eac[cb] = 0.f; }

    const int p0 = peptr[n], p1 = peptr[n + 1];

    for (int p = p0; p < p1; p += 32) {
        const unsigned short* ab = rbfT + (size_t)(p + 8 * lg) * 16 + l15;
        bf16x8 af = pack8(
            (unsigned int)ab[0]  | ((unsigned int)ab[16] << 16),
            (unsigned int)ab[32] | ((unsigned int)ab[48] << 16),
            (unsigned int)ab[64] | ((unsigned int)ab[80] << 16),
            (unsigned int)ab[96] | ((unsigned int)ab[112] << 16));

        bf16x8 a2f = (bf16x8){0,0,0,0,0,0,0,0};
        if (l15 == 0)
            a2f = *(const bf16x8*)(envs + p + 8 * lg);

        int4 j03 = *(const int4*)(js + p + 8 * lg);
        int4 j47 = *(const int4*)(js + p + 8 * lg + 4);

        const unsigned short* pb0 = phi + (size_t)j03.x * 128 + 64 * h + l15;
        const unsigned short* pb1 = phi + (size_t)j03.y * 128 + 64 * h + l15;
        const unsigned short* pb2 = phi + (size_t)j03.z * 128 + 64 * h + l15;
        const unsigned short* pb3 = phi + (size_t)j03.w * 128 + 64 * h + l15;
        const unsigned short* pb4 = phi + (size_t)j47.x * 128 + 64 * h + l15;
        const unsigned short* pb5 = phi + (size_t)j47.y * 128 + 64 * h + l15;
        const unsigned short* pb6 = phi + (size_t)j47.z * 128 + 64 * h + l15;
        const unsigned short* pb7 = phi + (size_t)j47.w * 128 + 64 * h + l15;

        #pragma unroll
        for (int cbi = 0; cbi < 4; ++cbi) {
            const int o = cbi * 16;
            unsigned int b0 = (unsigned int)pb0[o] | ((unsigned int)pb1[o] << 16);
            unsigned int b1 = (unsigned int)pb2[o] | ((unsigned int)pb3[o] << 16);
            unsigned int b2 = (unsigned int)pb4[o] | ((unsigned int)pb5[o] << 16);
            unsigned int b3 = (unsigned int)pb6[o] | ((unsigned int)pb7[o] << 16);
            bf16x8 bf = pack8(b0, b1, b2, b3);
            acc[cbi] = __builtin_amdgcn_mfma_f32_16x16x32_bf16(af, bf, acc[cbi], 0, 0, 0);
            f32x4 z = (f32x4){0, 0, 0, 0};
            z = __builtin_amdgcn_mfma_f32_16x16x32_bf16(a2f, bf, z, 0, 0, 0);
            eac[cbi] += z[0];
        }
    }

    #pragma unroll
    for (int cbi = 0; cbi < 4; ++cbi) {
        int col = 64 * h + cbi * 16 + l15;
        float part = acc[cbi][0] * distW[(lg * 4 + 0) * 128 + col];
        part = fmaf(acc[cbi][1], distW[(lg * 4 + 1) * 128 + col], part);
        part = fmaf(acc[cbi][2], distW[(lg * 4 + 2) * 128 + col], part);
        part = fmaf(acc[cbi][3], distW[(lg * 4 + 3) * 128 + col], part);
        if (lg == 0) part = fmaf(eac[cbi], distb[col], part);
        part += __shfl_xor(part, 16, 64);
        part += __shfl_xor(part, 32, 64);
        if (lane < 16) v[(size_t)n * 128 + col] = part;
    }
}

// ---------------------------------------------------------------------------
// Fused heads (r12-proven): bbA, bbT, scA, scS per node in one wave.
// ---------------------------------------------------------------------------
__global__ __launch_bounds__(256) void fused_heads_kernel(
    const float* __restrict__ S0,
    const float* __restrict__ bbaW1, const float* __restrict__ bbab1,
    const float* __restrict__ bbaW2, const float* __restrict__ bbab2,
    const float* __restrict__ bbtW1, const float* __restrict__ bbtb1,
    const float* __restrict__ bbtW2, const float* __restrict__ bbtb2,
    const float* __restrict__ scaW1, const float* __restrict__ scab1,
    const float* __restrict__ scaW2, const float* __restrict__ scab2,
    float* __restrict__ bbA, float* __restrict__ bbT,
    float* __restrict__ scA, float* __restrict__ scS, int N)
{
    const int wid = threadIdx.x >> 6;
    const int lane = threadIdx.x & 63;
    const int n = blockIdx.x * 4 + wid;
    if (n >= N) return;

    float x0 = S0[(size_t)n * 128 + lane];
    float x1 = S0[(size_t)n * 128 + 64 + lane];
    float s0 = silu_f(x0), s1 = silu_f(x1);

    // ---- bba (M=3, K=128) ----
    float ba[3];
    #pragma unroll
    for (int m = 0; m < 3; ++m)
        ba[m] = fmaf(s0, bbaW1[lane * 3 + m], s1 * bbaW1[(lane + 64) * 3 + m]);
    #pragma unroll
    for (int m = 0; m < 3; ++m)
        #pragma unroll
        for (int off = 32; off > 0; off >>= 1)
            ba[m] += __shfl_xor(ba[m], off, 64);
    float bbo[3];
    {
        float tm[3];
        #pragma unroll
        for (int m = 0; m < 3; ++m) tm[m] = silu_f(ba[m] + bbab1[m]);
        #pragma unroll
        for (int mm = 0; mm < 3; ++mm) {
            float o = bbab2[mm];
            #pragma unroll
            for (int m = 0; m < 3; ++m) o = fmaf(tm[m], bbaW2[m * 3 + mm], o);
            bbo[mm] = o;
        }
    }
    if (lane < 3) {
        float ov = bbo[0];
        if (lane == 1) ov = bbo[1];
        if (lane == 2) ov = bbo[2];
        bbA[(size_t)n * 3 + lane] = ov;
    }

    // ---- bbt (M=3, K=131 = S0 ++ bbA) ----
    float bt[3];
    #pragma unroll
    for (int m = 0; m < 3; ++m)
        bt[m] = fmaf(s0, bbtW1[lane * 3 + m], s1 * bbtW1[(lane + 64) * 3 + m]);
    #pragma unroll
    for (int m = 0; m < 3; ++m)
        #pragma unroll
        for (int off = 32; off > 0; off >>= 1)
            bt[m] += __shfl_xor(bt[m], off, 64);
    #pragma unroll
    for (int m = 0; m < 3; ++m)
        #pragma unroll
        for (int t = 0; t < 3; ++t)
            bt[m] = fmaf(silu_f(bbo[t]), bbtW1[(128 + t) * 3 + m], bt[m]);
    {
        float tm[3], bto[3];
        #pragma unroll
        for (int m = 0; m < 3; ++m) tm[m] = silu_f(bt[m] + bbtb1[m]);
        #pragma unroll
        for (int mm = 0; mm < 3; ++mm) {
            float o = bbtb2[mm];
            #pragma unroll
            for (int m = 0; m < 3; ++m) o = fmaf(tm[m], bbtW2[m * 3 + mm], o);
            bto[mm] = o;
        }
        if (lane < 3) {
            float ov = bto[0];
            if (lane == 1) ov = bto[1];
            if (lane == 2) ov = bto[2];
            bbT[(size_t)n * 3 + lane] = ov;
        }
    }

    // ---- sca (M=10, K=128) ----
    float sa[10];
    #pragma unroll
    for (int m = 0; m < 10; ++m)
        sa[m] = fmaf(s0, scaW1[lane * 10 + m], s1 * scaW1[(lane + 64) * 10 + m]);
    #pragma unroll
    for (int m = 0; m < 10; ++m)
        #pragma unroll
        for (int off = 32; off > 0; off >>= 1)
            sa[m] += __shfl_xor(sa[m], off, 64);
    float sco[10];
    {
        float tm[10];
        #pragma unroll
        for (int m = 0; m < 10; ++m) tm[m] = silu_f(sa[m] + scab1[m]);
        #pragma unroll
        for (int mm = 0; mm < 10; ++mm) {
            float o = scab2[mm];
            #pragma unroll
            for (int m = 0; m < 10; ++m) o = fmaf(tm[m], scaW2[m * 10 + mm], o);
            sco[mm] = o;
        }
    }
    float scv = sco[0];
    #pragma unroll
    for (int m = 1; m < 10; ++m)
        if (lane == m) scv = sco[m];
    if (lane < 10) scA[(size_t)n * 10 + lane] = scv;

    // ---- scS = concat(S0, scA, pad) ----
    scS[(size_t)n * 140 + lane] = x0;
    scS[(size_t)n * 140 + 64 + lane] = x1;
    if (lane < 12) scS[(size_t)n * 140 + 128 + lane] = (lane < 10) ? scv : 0.0f;
}

extern "C" void kernel_launch(void* const* d_in, const int* in_sizes, int n_in,
                              void* d_out, int out_size, void* d_ws, size_t ws_size,
                              hipStream_t stream)
{
    const int*   cg_z        = (const int*)d_in[0];
    const float* cg_xyz      = (const float*)d_in[1];
    const int*   nbr         = (const int*)d_in[2];
    // d_in[3] = mapping (unused by reference)
    const float* S_in        = (const float*)d_in[4];
    const float* res_embed   = (const float*)d_in[5];
    const float* msg_W1      = (const float*)d_in[6];
    const float* msg_b1      = (const float*)d_in[7];
    const float* msg_W2      = (const float*)d_in[8];
    const float* msg_b2      = (const float*)d_in[9];
    const float* dist_W      = (const float*)d_in[10];
    const float* dist_b      = (const float*)d_in[11];
    const float* dense_W1    = (const float*)d_in[12];
    const float* dense_b1    = (const float*)d_in[13];
    const float* dense_W2    = (const float*)d_in[14];
    const float* dense_b2    = (const float*)d_in[15];
    const float* bb_dist_emb = (const float*)d_in[16];
    const float* sc_dist_emb = (const float*)d_in[17];
    const float* bba_W1      = (const float*)d_in[18];
    const float* bba_b1      = (const float*)d_in[19];
    const float* bba_W2      = (const float*)d_in[20];
    const float* bba_b2      = (const float*)d_in[21];
    const float* sca_W1      = (const float*)d_in[22];
    const float* sca_b1      = (const float*)d_in[23];
    const float* sca_W2      = (const float*)d_in[24];
    const float* sca_b2      = (const float*)d_in[25];
    const float* bbt_W1      = (const float*)d_in[26];
    const float* bbt_b1      = (const float*)d_in[27];
    const float* bbt_W2      = (const float*)d_in[28];
    const float* bbt_b2      = (const float*)d_in[29];
    const float* sct_W1      = (const float*)d_in[30];
    const float* sct_b1      = (const float*)d_in[31];
    const float* sct_W2      = (const float*)d_in[32];
    const float* sct_b2      = (const float*)d_in[33];
    const float* ft_W1       = (const float*)d_in[34];
    const float* ft_b1       = (const float*)d_in[35];
    const float* ft_W2       = (const float*)d_in[36];
    const float* ft_b2       = (const float*)d_in[37];

    const int N = in_sizes[0];
    const int E = in_sizes[2] / 2;
    const int EPAD = ((E + 31 * N) / 32) * 32 + 32;   // padded-edge upper bound

    unsigned short* WB   = (unsigned short*)d_ws;                      // 24*WSLOT
    unsigned short* rbfT = WB + (size_t)24 * WSLOT;                    // EPAD*16 (contiguous records)
    unsigned short* envs = rbfT + (size_t)EPAD * 16;                   // EPAD
    int*            js   = (int*)(envs + (size_t)EPAD);                // EPAD
    float* ws   = (float*)(js + (size_t)EPAD);
    float* S0   = ws;  ws += (size_t)N * 128;
    float* V    = ws;  ws += (size_t)N * 128;
    float* scS  = ws;  ws += (size_t)N * 140;
    float* bbA  = ws;  ws += (size_t)N * 3;
    float* bbT  = ws;  ws += (size_t)N * 3;
    float* scA  = ws;  ws += (size_t)N * 10;
    float* scT  = ws;  ws += (size_t)N * 10;   // unused (kept for layout stability)
    __hip_bfloat16* PHI = (__hip_bfloat16*)ws;  ws += (size_t)N * 64;  // N*128 bf16
    int* peptr  = (int*)ws;  ws = (float*)((int*)ws + (N + 1));
    int* counts = (int*)ws;  ws = (float*)((int*)ws + N);
    int* cursor = (int*)ws;  ws = (float*)((int*)ws + N);
    (void)scT;

    // Zero padded edge region (rbfT|envs|js contiguous) + counts/cursor.
    (void)hipMemsetAsync(rbfT, 0, (size_t)EPAD * 38, stream);
    (void)hipMemsetAsync(counts, 0, (size_t)2 * N * sizeof(int), stream);

    prep_weights_kernel<<<dim3(64, 12), 256, 0, stream>>>(
        msg_W1, msg_W2, dense_W1, dense_W2, WB);

    hist_kernel<<<DIV_UP(E, 256), 256, 0, stream>>>(nbr, counts, E);
    scan_kernel<<<1, 1024, 0, stream>>>(counts, peptr, N);
    geom_scatter_kernel<<<DIV_UP(E, 256), 256, 0, stream>>>(
        nbr, cg_xyz, peptr, cursor, rbfT, envs, js, E);

    concat_s_kernel<<<DIV_UP(N * 128, 256), 256, 0, stream>>>(S_in, res_embed, cg_z, S0, N);

    #define WHI(kind, conv) (WB + (size_t)(2 * ((kind) * 3 + (conv))) * WSLOT)
    #define WLO(kind, conv) (WB + (size_t)(2 * ((kind) * 3 + (conv)) + 1) * WSLOT)

    for (int i = 0; i < 3; ++i) {
        mlp2_mfma_kernel<48, false, false, __hip_bfloat16>
            <<<DIV_UP(N, 48), 256, 0, stream>>>(
            S0, WHI(0, i), WLO(0, i), msg_b1 + i * 128,
            WHI(1, i), WLO(1, i), msg_b2 + i * 128, PHI, N);
        gather_mfma_kernel<<<DIV_UP(2 * N, 4), 256, 0, stream>>>(
            peptr, rbfT, envs, js, (const unsigned short*)PHI,
            dist_W + (size_t)i * 16 * 128, dist_b + i * 128, V, N);
        mlp2_mfma_kernel<48, true, true, float>
            <<<DIV_UP(N, 48), 256, 0, stream>>>(
            V, WHI(2, i), WLO(2, i), dense_b1 + i * 128,
            WHI(3, i), WLO(3, i), dense_b2 + i * 128, S0, N);
    }

    fused_heads_kernel<<<DIV_UP(N, 4), 256, 0, stream>>>(
        S0,
        bba_W1, bba_b1, bba_W2, bba_b2,
        bbt_W1, bbt_b1, bbt_W2, bbt_b2,
        sca_W1, sca_b1, sca_W2, sca_b2,
        bbA, bbT, scA, scS, N);

    sct_fused_kernel<<<DIV_UP(N, 16), 256, 0, stream>>>(
        scS, sct_W1, sct_b1, sct_W2, sct_b2,
        ft_W1, ft_b1, ft_W2, ft_b2,
        cg_z, bb_dist_emb, sc_dist_emb, bbA, bbT, scA,
        (float*)d_out, N);

    #undef WHI
    #undef WLO
}